// Round 1
// baseline (382.262 us; speedup 1.0000x reference)
//
#include <hip/hip_runtime.h>
#include <math.h>

namespace {
constexpr int NSAMP = 32768;
constexpr int NMASK = NSAMP - 1;
constexpr int BTOT  = 32;   // 4 groups * 8 events
constexpr float MIN_F_F = (float)(30.0 / 11025.0);
constexpr float SPAN_F  = (float)(3000.0 / 11025.0 - 30.0 / 11025.0);
constexpr float PI_F    = 3.14159265358979323846f;
constexpr double TWO_PI  = 6.283185307179586476925287;
constexpr double INV_2PI = 0.159154943091895335768884;
constexpr float INV_SQRT_N = 0.00552427172801990295f; // 1/sqrt(32768)

// ws layout (bytes)
constexpr size_t OFF_P  = 0;                        // double [32][64][128]  2 MB
constexpr size_t OFF_V  = OFF_P + 32*64*128*8;      // float  [32][64][128]  1 MB
constexpr size_t OFF_T  = OFF_V + 32*64*128*4;      // float  [32][64][128]  1 MB
constexpr size_t OFF_A  = OFF_T + 32*64*128*4;      // float  [32][128][128] 2 MB
constexpr size_t OFF_M  = OFF_A + 32*128*128*4;     // uint   [2048]
constexpr size_t OFF_SW = OFF_M + 2048*4;           // float  [32]
constexpr size_t OFF_SH = OFF_SW + 32*4;            // int    [32]
}

__device__ __forceinline__ float sigmoidf_(float z) { return 1.0f / (1.0f + expf(-z)); }
__device__ __forceinline__ float gumbelf_(float u) {
    return -logf(-logf(u + 1e-10f) + 1e-10f);
}

// ---------------- amp = (x @ W_amp + b_amp)^2, [32][128ch][128fr] ----------------
__launch_bounds__(256)
__global__ void amp_kernel(const float* __restrict__ x, const float* __restrict__ Wamp,
                           const float* __restrict__ bamp, float* __restrict__ ampo) {
    int j = blockIdx.x * 256 + threadIdx.x;  // 0..16383
    __shared__ float xs[32 * 128];
    for (int i = threadIdx.x; i < 32 * 128; i += 256) xs[i] = x[i];
    __syncthreads();
    float acc[32];
    float bj = bamp[j];
#pragma unroll
    for (int b = 0; b < 32; ++b) acc[b] = bj;
    for (int d = 0; d < 128; ++d) {
        float wv = Wamp[(size_t)d * 16384 + j];
#pragma unroll
        for (int b = 0; b < 32; ++b) acc[b] = fmaf(xs[b * 128 + d], wv, acc[b]);
    }
#pragma unroll
    for (int b = 0; b < 32; ++b) {
        float a = acc[b];
        ampo[(size_t)b * 16384 + j] = a * a;
    }
}

// ---------------- per-b prep: gates, f0, freq table, phase prefixes, FIR taps ----
__launch_bounds__(128)
__global__ void prep_kernel(const float* __restrict__ x,
                            const float* __restrict__ Wsw, const float* __restrict__ bsw,
                            const float* __restrict__ Wf0, const float* __restrict__ bf0,
                            const float* __restrict__ Wfv, const float* __restrict__ bfv,
                            const float* __restrict__ Wloc, const float* __restrict__ bloc,
                            const float* __restrict__ usw, const float* __restrict__ uloc,
                            double* __restrict__ Pws, float* __restrict__ vfreq,
                            float* __restrict__ taps, float* __restrict__ swb,
                            int* __restrict__ shiftb) {
    int b = blockIdx.x, tid = threadIdx.x;  // 128 threads
    __shared__ float xs[128], f0t[128];
    __shared__ float redA[128]; __shared__ int redI[128];
    __shared__ float red0[128], red1[128], red2[128];
    xs[tid] = x[b * 128 + tid];
    __syncthreads();

    // per-frame dots: f0_var logits and loc logits
    float aFv = bfv[tid], aLoc = bloc[tid];
    for (int d = 0; d < 128; ++d) {
        float xv = xs[d];
        aFv  = fmaf(xv, Wfv[d * 128 + tid], aFv);
        aLoc = fmaf(xv, Wloc[d * 128 + tid], aLoc);
    }
    float f0var = sigmoidf_(aFv) * 2.0f - 1.0f;
    float yloc = sigmoidf_(aLoc) + gumbelf_(uloc[b * 128 + tid]);

    // argmax over 128 frames (softmax is monotone -> argmax of logits+gumbel)
    redA[tid] = yloc; redI[tid] = tid;
    __syncthreads();
    for (int off = 64; off > 0; off >>= 1) {
        if (tid < off) {
            if (redA[tid + off] > redA[tid]) { redA[tid] = redA[tid + off]; redI[tid] = redI[tid + off]; }
        }
        __syncthreads();
    }
    int frame = redI[0];

    // three small dots: sw logits (2) and f0 logit
    red0[tid] = xs[tid] * Wsw[tid * 2 + 0];
    red1[tid] = xs[tid] * Wsw[tid * 2 + 1];
    red2[tid] = xs[tid] * Wf0[tid];
    __syncthreads();
    for (int off = 64; off > 0; off >>= 1) {
        if (tid < off) { red0[tid] += red0[tid + off]; red1[tid] += red1[tid + off]; red2[tid] += red2[tid + off]; }
        __syncthreads();
    }
    float l0 = red0[0] + bsw[0], l1 = red1[0] + bsw[1];
    float g0 = gumbelf_(usw[b * 2 + 0]), g1 = gumbelf_(usw[b * 2 + 1]);
    float swv = (l0 + g0 >= l1 + g1) ? 1.0f : 0.0f;  // argmax ties -> first
    float sg = sigmoidf_(red2[0] + bf0[0]);
    float f0v = MIN_F_F + (sg * sg) * SPAN_F;
    if (tid == 0) { swb[b] = swv; shiftb[b] = frame * 256; }

    f0t[tid] = f0v + f0var * (f0v * 0.01f);
    __syncthreads();

    if (tid < 64) {
        int h = tid;
        float hf = (float)(h + 1);
        size_t base = ((size_t)b * 64 + h) * 128;
        double P = 0.0;
        float vprev = 0.0f, v0 = 0.0f;
        for (int k = 0; k < 128; ++k) {
            float v = f0t[k] * hf;
            v = (v > 1.0f) ? 0.0f : v * PI_F;
            vfreq[base + k] = v;
            if (k == 0) { v0 = v; P = 128.0 * (double)v; }
            else        { P += 128.0 * ((double)vprev + (double)v); }
            Pws[base + k] = P;  // prefix phase at start of segment k (k=127: tail prefix)
            vprev = v;
        }
        for (int k = 0; k < 128; ++k) {
            float hwk = 0.54f - 0.46f * cosf(6.2831853071795864769f * (float)k / 128.0f);
            float sv = (float)sin((double)(k + 1) * (double)v0);
            taps[base + k] = sv * hwk * INV_SQRT_N;
        }
    }
}

// ---------------- pass 1: circular FIR, per-(b,h) row max ----------------
__launch_bounds__(256)
__global__ void convmax_kernel(const float* __restrict__ noise_u,
                               const float* __restrict__ taps,
                               const float* __restrict__ swb,
                               unsigned int* __restrict__ maxb) {
    int tile = blockIdx.x, b = blockIdx.y, tid = threadIdx.x;
    if (swb[b] == 0.0f) return;
    __shared__ float tapsL[64 * 128];
    __shared__ float wpad[432];  // 383 window values, XOR-ish padded (s + s>>3)
    for (int i = tid; i < 8192; i += 256) tapsL[i] = taps[(size_t)b * 8192 + i];
    int T = tile * 256;
    for (int s = tid; s < 383; s += 256) {
        float nv = noise_u[(size_t)b * NSAMP + ((T - 127 + s) & NMASK)];
        wpad[s + (s >> 3)] = nv * 2.0f - 1.0f;
    }
    __syncthreads();
    int hg = tid >> 5, jl = tid & 31, j0 = jl * 8;
    for (int hh = 0; hh < 8; ++hh) {
        int h = hh * 8 + hg;
        const float* tp = &tapsL[h * 128];
        float acc[8] = {0, 0, 0, 0, 0, 0, 0, 0};
        float win[8];
#pragma unroll
        for (int i = 0; i < 8; ++i) { int s = 127 + j0 + i; win[(127 + i) & 7] = wpad[s + (s >> 3)]; }
#pragma unroll
        for (int k = 0; k < 128; ++k) {
            float tap = tp[k];
#pragma unroll
            for (int i = 0; i < 8; ++i) acc[i] = fmaf(tap, win[(127 + i - k) & 7], acc[i]);
            if (k < 127) { int s = 126 + j0 - k; win[(126 - k) & 7] = wpad[s + (s >> 3)]; }
        }
        float m = 0.0f;
#pragma unroll
        for (int i = 0; i < 8; ++i) m = fmaxf(m, fabsf(acc[i]));
#pragma unroll
        for (int off = 1; off < 32; off <<= 1) m = fmaxf(m, __shfl_xor(m, off));
        if (jl == 0) atomicMax(&maxb[b * 64 + h], __float_as_uint(m));
    }
}

// ---------------- pass 2: fused conv + harm sine + amp lerp + reduce + shift ----
__launch_bounds__(256)
__global__ void final_kernel(const float* __restrict__ noise_u,
                             const double* __restrict__ Pws, const float* __restrict__ vfreq,
                             const float* __restrict__ taps, const float* __restrict__ amp,
                             const unsigned int* __restrict__ maxb,
                             const float* __restrict__ swb, const int* __restrict__ shiftb,
                             float* __restrict__ out) {
    int tile = blockIdx.x, b = blockIdx.y, tid = threadIdx.x;
    int T = tile * 256;
    if (swb[b] == 0.0f) {  // gated off: whole row is exactly zero
        out[(size_t)b * NSAMP + T + tid] = 0.0f;
        return;
    }
    __shared__ float tapsL[64 * 128];
    __shared__ float wpad[432];
    __shared__ float ampf[3 * 128];  // [d][ch], frames tile-1..tile+1 (clamped)
    __shared__ float invnL[64];
    __shared__ float accL[8][256];
    for (int i = tid; i < 8192; i += 256) tapsL[i] = taps[(size_t)b * 8192 + i];
    for (int s = tid; s < 383; s += 256) {
        float nv = noise_u[(size_t)b * NSAMP + ((T - 127 + s) & NMASK)];
        wpad[s + (s >> 3)] = nv * 2.0f - 1.0f;
    }
    for (int idx = tid; idx < 384; idx += 256) {
        int d = idx >> 7, ch = idx & 127;
        int fr = min(max(tile - 1 + d, 0), 127);
        ampf[d * 128 + ch] = amp[(size_t)b * 16384 + ch * 128 + fr];
    }
    if (tid < 64) invnL[tid] = 1.0f / (__uint_as_float(maxb[b * 64 + tid]) + 1e-8f);
    __syncthreads();

    int hg = tid >> 5, jl = tid & 31, j0 = jl * 8;
    // per-sample lerp weights (shared by all channels; f32, bit-matches reference)
    float wgt[8]; int slo[8], shi[8];
#pragma unroll
    for (int i = 0; i < 8; ++i) {
        int t = T + j0 + i;
        float coords = ((float)t + 0.5f) * (1.0f / 256.0f) - 0.5f;
        coords = fminf(fmaxf(coords, 0.0f), 127.0f);
        float lof = floorf(coords);
        int lo = (int)lof;
        int hi = min(lo + 1, 127);
        wgt[i] = coords - lof;
        slo[i] = lo - (tile - 1);
        shi[i] = hi - (tile - 1);
    }
    int t0 = T + j0;
    float tot[8] = {0, 0, 0, 0, 0, 0, 0, 0};
    for (int hh = 0; hh < 8; ++hh) {
        int h = hh * 8 + hg;
        // FIR (sliding register window)
        const float* tp = &tapsL[h * 128];
        float acc[8] = {0, 0, 0, 0, 0, 0, 0, 0};
        float win[8];
#pragma unroll
        for (int i = 0; i < 8; ++i) { int s = 127 + j0 + i; win[(127 + i) & 7] = wpad[s + (s >> 3)]; }
#pragma unroll
        for (int k = 0; k < 128; ++k) {
            float tap = tp[k];
#pragma unroll
            for (int i = 0; i < 8; ++i) acc[i] = fmaf(tap, win[(127 + i - k) & 7], acc[i]);
            if (k < 127) { int s = 126 + j0 - k; win[(126 - k) & 7] = wpad[s + (s >> 3)]; }
        }
        // closed-form phase + sine (f64 phase, exact cumsum of piecewise-linear freq)
        size_t base = ((size_t)b * 64 + h) * 128;
        float sv[8];
        if (t0 < 128) {
            float v0 = vfreq[base];
#pragma unroll
            for (int i = 0; i < 8; ++i) {
                double p = (double)(t0 + i + 1) * (double)v0;
                double rev = p * INV_2PI; rev -= floor(rev);
                sv[i] = __sinf((float)(rev * TWO_PI));
            }
        } else if (t0 >= 32640) {
            float v127 = vfreq[base + 127];
            double Pt = Pws[base + 127];
#pragma unroll
            for (int i = 0; i < 8; ++i) {
                double p = Pt + (double)(t0 + i - 32639) * (double)v127;
                double rev = p * INV_2PI; rev -= floor(rev);
                sv[i] = __sinf((float)(rev * TWO_PI));
            }
        } else {
            int u0 = t0 - 128;
            int s = u0 >> 8, m0 = u0 & 255;
            float vs = vfreq[base + s], vs1 = vfreq[base + s + 1];
            double Pb = Pws[base + s];
            double dv = (double)(vs1 - vs) * (1.0 / 512.0);
#pragma unroll
            for (int i = 0; i < 8; ++i) {
                double mp1 = (double)(m0 + i + 1);
                double p = Pb + mp1 * (double)vs + dv * mp1 * mp1;
                double rev = p * INV_2PI; rev -= floor(rev);
                sv[i] = __sinf((float)(rev * TWO_PI));
            }
        }
        float invn = invnL[h];
#pragma unroll
        for (int i = 0; i < 8; ++i) {
            float w1 = wgt[i], w0 = 1.0f - w1;
            float aA = ampf[slo[i] * 128 + h] * w0 + ampf[shi[i] * 128 + h] * w1;
            float aB = ampf[slo[i] * 128 + 64 + h] * w0 + ampf[shi[i] * 128 + 64 + h] * w1;
            tot[i] += sv[i] * aA + acc[i] * invn * aB;
        }
    }
#pragma unroll
    for (int i = 0; i < 8; ++i) accL[hg][j0 + i] = tot[i];
    __syncthreads();
    float r = 0.0f;
#pragma unroll
    for (int g2 = 0; g2 < 8; ++g2) r += accL[g2][tid];
    int pos = (T + tid + shiftb[b]) & NMASK;  // final fft_convolve == circular shift
    out[(size_t)b * NSAMP + pos] = r;
}

extern "C" void kernel_launch(void* const* d_in, const int* in_sizes, int n_in,
                              void* d_out, int out_size, void* d_ws, size_t ws_size,
                              hipStream_t stream) {
    const float* x     = (const float*)d_in[0];
    const float* Wsw   = (const float*)d_in[1];
    const float* bsw   = (const float*)d_in[2];
    const float* Wf0   = (const float*)d_in[3];
    const float* bf0   = (const float*)d_in[4];
    const float* Wfv   = (const float*)d_in[5];
    const float* bfv   = (const float*)d_in[6];
    const float* Wamp  = (const float*)d_in[7];
    const float* bamp  = (const float*)d_in[8];
    const float* Wloc  = (const float*)d_in[9];
    const float* bloc  = (const float*)d_in[10];
    const float* usw   = (const float*)d_in[11];
    const float* uloc  = (const float*)d_in[12];
    const float* noise = (const float*)d_in[13];

    char* ws = (char*)d_ws;
    double* Pws   = (double*)(ws + OFF_P);
    float*  vfreq = (float*)(ws + OFF_V);
    float*  taps  = (float*)(ws + OFF_T);
    float*  amp   = (float*)(ws + OFF_A);
    unsigned* maxb = (unsigned*)(ws + OFF_M);
    float*  swb   = (float*)(ws + OFF_SW);
    int*    shiftb = (int*)(ws + OFF_SH);
    float*  out = (float*)d_out;

    hipMemsetAsync(maxb, 0, 2048 * sizeof(unsigned), stream);
    amp_kernel<<<dim3(64), 256, 0, stream>>>(x, Wamp, bamp, amp);
    prep_kernel<<<dim3(32), 128, 0, stream>>>(x, Wsw, bsw, Wf0, bf0, Wfv, bfv, Wloc, bloc,
                                              usw, uloc, Pws, vfreq, taps, swb, shiftb);
    convmax_kernel<<<dim3(128, 32), 256, 0, stream>>>(noise, taps, swb, maxb);
    final_kernel<<<dim3(128, 32), 256, 0, stream>>>(noise, Pws, vfreq, taps, amp, maxb,
                                                    swb, shiftb, out);
}

// Round 2
// 165.808 us; speedup vs baseline: 2.3055x; 2.3055x over previous
//
#include <hip/hip_runtime.h>
#include <math.h>

typedef __attribute__((ext_vector_type(8))) short short8v;   // 8 bf16 (4 VGPRs)
typedef __attribute__((ext_vector_type(4))) float f32x4;

namespace {
constexpr int NSAMP = 32768;
constexpr int NMASK = NSAMP - 1;
constexpr float MIN_F_F = (float)(30.0 / 11025.0);
constexpr float SPAN_F  = (float)(3000.0 / 11025.0 - 30.0 / 11025.0);
constexpr float PI_F    = 3.14159265358979323846f;
constexpr double TWO_PI  = 6.283185307179586476925287;
constexpr double INV_2PI = 0.159154943091895335768884;
constexpr float INV_SQRT_N = 0.00552427172801990295f; // 1/sqrt(32768)

// ws layout (bytes)
constexpr size_t OFF_P  = 0;                         // double Pws   [32][64][128]  2 MB
constexpr size_t OFF_V  = OFF_P  + 32*64*128*8;      // float  vfreq [32][64][128]  1 MB
constexpr size_t OFF_TA = OFF_V  + 32*64*128*4;      // u16    tapsA [32][64][128]  512 KB (bf16, reversed+swizzled)
constexpr size_t OFF_A  = OFF_TA + 32*64*128*2;      // float  ampT  [32][128fr][128ch] 2 MB
constexpr size_t OFF_M  = OFF_A  + 32*128*128*4;     // uint   maxb  [2048]
constexpr size_t OFF_SW = OFF_M  + 2048*4;           // float  swb   [32]
constexpr size_t OFF_SH = OFF_SW + 32*4;             // int    shiftb[32]
}

__device__ __forceinline__ float sigmoidf_(float z) { return 1.0f / (1.0f + expf(-z)); }
__device__ __forceinline__ float gumbelf_(float u) { return -logf(-logf(u + 1e-10f) + 1e-10f); }
__device__ __forceinline__ unsigned short f2bf(float f) {
    unsigned u = __float_as_uint(f);
    return (unsigned short)((u + 0x7FFFu + ((u >> 16) & 1u)) >> 16);
}

// ---------------- amp = (x @ W_amp + b_amp)^2 -> transposed [32][fr][ch] ----------------
__launch_bounds__(256)
__global__ void amp_kernel(const float* __restrict__ x, const float* __restrict__ Wamp,
                           const float* __restrict__ bamp, float* __restrict__ ampT) {
    int j = blockIdx.x * 256 + threadIdx.x;  // 0..16383 ; ch = j>>7, fr = j&127
    __shared__ float xs[32 * 128];
    for (int i = threadIdx.x; i < 32 * 128; i += 256) xs[i] = x[i];
    __syncthreads();
    float acc[32];
    float bj = bamp[j];
#pragma unroll
    for (int b = 0; b < 32; ++b) acc[b] = bj;
    for (int d = 0; d < 128; ++d) {
        float wv = Wamp[(size_t)d * 16384 + j];
#pragma unroll
        for (int b = 0; b < 32; ++b) acc[b] = fmaf(xs[b * 128 + d], wv, acc[b]);
    }
    int ch = j >> 7, fr = j & 127;
#pragma unroll
    for (int b = 0; b < 32; ++b) {
        float a = acc[b];
        ampT[(size_t)b * 16384 + fr * 128 + ch] = a * a;
    }
}

// ---------------- per-b prep: gates, f0, freq table, phase prefixes, bf16 FIR taps ----
__launch_bounds__(128)
__global__ void prep_kernel(const float* __restrict__ x,
                            const float* __restrict__ Wsw, const float* __restrict__ bsw,
                            const float* __restrict__ Wf0, const float* __restrict__ bf0,
                            const float* __restrict__ Wfv, const float* __restrict__ bfv,
                            const float* __restrict__ Wloc, const float* __restrict__ bloc,
                            const float* __restrict__ usw, const float* __restrict__ uloc,
                            double* __restrict__ Pws, float* __restrict__ vfreq,
                            unsigned short* __restrict__ tapsA, float* __restrict__ swb,
                            int* __restrict__ shiftb) {
    int b = blockIdx.x, tid = threadIdx.x;  // 128 threads
    __shared__ float xs[128], f0t[128];
    __shared__ float redA[128]; __shared__ int redI[128];
    __shared__ float red0[128], red1[128], red2[128];
    xs[tid] = x[b * 128 + tid];
    __syncthreads();

    float aFv = bfv[tid], aLoc = bloc[tid];
    for (int d = 0; d < 128; ++d) {
        float xv = xs[d];
        aFv  = fmaf(xv, Wfv[d * 128 + tid], aFv);
        aLoc = fmaf(xv, Wloc[d * 128 + tid], aLoc);
    }
    float f0var = sigmoidf_(aFv) * 2.0f - 1.0f;
    float yloc = sigmoidf_(aLoc) + gumbelf_(uloc[b * 128 + tid]);

    redA[tid] = yloc; redI[tid] = tid;
    __syncthreads();
    for (int off = 64; off > 0; off >>= 1) {
        if (tid < off) {
            if (redA[tid + off] > redA[tid]) { redA[tid] = redA[tid + off]; redI[tid] = redI[tid + off]; }
        }
        __syncthreads();
    }
    int frame = redI[0];

    red0[tid] = xs[tid] * Wsw[tid * 2 + 0];
    red1[tid] = xs[tid] * Wsw[tid * 2 + 1];
    red2[tid] = xs[tid] * Wf0[tid];
    __syncthreads();
    for (int off = 64; off > 0; off >>= 1) {
        if (tid < off) { red0[tid] += red0[tid + off]; red1[tid] += red1[tid + off]; red2[tid] += red2[tid + off]; }
        __syncthreads();
    }
    float l0 = red0[0] + bsw[0], l1 = red1[0] + bsw[1];
    float g0 = gumbelf_(usw[b * 2 + 0]), g1 = gumbelf_(usw[b * 2 + 1]);
    float swv = (l0 + g0 >= l1 + g1) ? 1.0f : 0.0f;
    float sg = sigmoidf_(red2[0] + bf0[0]);
    float f0v = MIN_F_F + (sg * sg) * SPAN_F;
    if (tid == 0) { swb[b] = swv; shiftb[b] = frame * 256; }

    f0t[tid] = f0v + f0var * (f0v * 0.01f);
    __syncthreads();

    if (tid < 64) {
        int h = tid;
        float hf = (float)(h + 1);
        size_t base = ((size_t)b * 64 + h) * 128;
        double P = 0.0;
        float vprev = 0.0f, v0 = 0.0f;
        for (int k = 0; k < 128; ++k) {
            float v = f0t[k] * hf;
            v = (v > 1.0f) ? 0.0f : v * PI_F;
            vfreq[base + k] = v;
            if (k == 0) { v0 = v; P = 128.0 * (double)v; }
            else        { P += 128.0 * ((double)vprev + (double)v); }
            Pws[base + k] = P;
            vprev = v;
        }
        // taps, bf16, reversed within 8-groups + 16B-chunk XOR swizzle by (h&7)
        for (int k = 0; k < 128; ++k) {
            float hwk = 0.54f - 0.46f * cosf(6.2831853071795864769f * (float)k / 128.0f);
            float sv = (float)sin((double)(k + 1) * (double)v0);
            float tv = sv * hwk * INV_SQRT_N;
            int c = k >> 3, e = 7 - (k & 7);
            tapsA[(base << 0) + 8 * (c ^ (h & 7)) + e] = f2bf(tv);
        }
    }
}

// Conv core notes:
//   k-fill convention (same for A and B, so any HW k-permutation cancels):
//     frag[r] corresponds to logical k = 32*ks + 8*(lane>>4) + (7 - r)
//   A (taps) stored pre-reversed -> one aligned b128 per (mt,ks)
//   B: wsh[s][t] = w[t+s], chunk c stored at c^s -> one aligned, conflict-free b128

// ---------------- pass 1: MFMA circular FIR, per-(b,h) row max ----------------
__launch_bounds__(256)
__global__ void convmax_kernel(const float* __restrict__ noise,
                               const unsigned short* __restrict__ tapsA,
                               const float* __restrict__ swb,
                               unsigned int* __restrict__ maxb) {
    int b = blockIdx.y;
    if (swb[b] == 0.0f) return;
    int T = blockIdx.x * 512, tid = threadIdx.x;
    __shared__ short tapsL[64 * 128];
    __shared__ short wsh[8][640];
    __shared__ float wf[640];
    __shared__ unsigned maxL[64];
    if (tid < 64) maxL[tid] = 0u;
    for (int i = tid; i < 640; i += 256)
        wf[i] = noise[(size_t)b * NSAMP + ((T - 127 + i) & NMASK)] * 2.0f - 1.0f;
    {
        const short8v* src = (const short8v*)(tapsA + ((size_t)b << 13));
        short8v* dst = (short8v*)tapsL;
        for (int i = tid; i < 1024; i += 256) dst[i] = src[i];
    }
    __syncthreads();
    for (int idx = tid; idx < 640; idx += 256) {
        int c = idx >> 3, s = idx & 7;
        short8v v;
#pragma unroll
        for (int e = 0; e < 8; ++e) {
            int t = 8 * c + e + s; t = t < 640 ? t : 639;
            v[e] = (short)f2bf(wf[t]);
        }
        *(short8v*)&wsh[s][8 * (c ^ s)] = v;
    }
    __syncthreads();
    int lane = tid & 63, w = tid >> 6;
    int g = lane >> 4, col = lane & 15, s_l = lane & 7, b3 = (lane >> 3) & 1;
    short8v fa[4][4];
#pragma unroll
    for (int mt = 0; mt < 4; ++mt)
#pragma unroll
        for (int ks = 0; ks < 4; ++ks) {
            int row = 16 * mt + col;
            int ch = (4 * ks + g) ^ (row & 7);
            fa[mt][ks] = *(const short8v*)&tapsL[row * 128 + 8 * ch];
        }
    float rm[4][4];
#pragma unroll
    for (int mt = 0; mt < 4; ++mt)
#pragma unroll
        for (int q = 0; q < 4; ++q) rm[mt][q] = 0.0f;
    for (int ntl = 0; ntl < 8; ++ntl) {
        int nt = w * 8 + ntl;
        short8v fb[4];
#pragma unroll
        for (int ks = 0; ks < 4; ++ks) {
            int t0 = 120 + 16 * nt - 32 * ks - 8 * g + 8 * b3;
            int ch = (t0 >> 3) ^ s_l;
            fb[ks] = *(const short8v*)&wsh[s_l][8 * ch];
        }
        f32x4 acc[4] = {{0,0,0,0},{0,0,0,0},{0,0,0,0},{0,0,0,0}};
#pragma unroll
        for (int ks = 0; ks < 4; ++ks)
#pragma unroll
            for (int mt = 0; mt < 4; ++mt)
                acc[mt] = __builtin_amdgcn_mfma_f32_16x16x32_bf16(fa[mt][ks], fb[ks], acc[mt], 0, 0, 0);
#pragma unroll
        for (int mt = 0; mt < 4; ++mt)
#pragma unroll
            for (int q = 0; q < 4; ++q) rm[mt][q] = fmaxf(rm[mt][q], fabsf(acc[mt][q]));
    }
#pragma unroll
    for (int mt = 0; mt < 4; ++mt)
#pragma unroll
        for (int q = 0; q < 4; ++q) {
            float m = rm[mt][q];
            m = fmaxf(m, __shfl_xor(m, 1));
            m = fmaxf(m, __shfl_xor(m, 2));
            m = fmaxf(m, __shfl_xor(m, 4));
            m = fmaxf(m, __shfl_xor(m, 8));
            if (col == 0) atomicMax(&maxL[16 * mt + 4 * g + q], __float_as_uint(m));
        }
    __syncthreads();
    if (tid < 64) atomicMax(&maxb[b * 64 + tid], maxL[tid]);
}

// ---------------- pass 2: fused MFMA conv + closed-form sine + amp lerp + reduce + shift ----
__launch_bounds__(256)
__global__ void final_kernel(const float* __restrict__ noise,
                             const unsigned short* __restrict__ tapsA,
                             const double* __restrict__ Pws, const float* __restrict__ vfreq,
                             const float* __restrict__ ampT,
                             const unsigned int* __restrict__ maxb,
                             const float* __restrict__ swb, const int* __restrict__ shiftb,
                             float* __restrict__ out) {
    int b = blockIdx.y;
    int T = blockIdx.x * 512, tid = threadIdx.x;
    if (swb[b] == 0.0f) {
        out[(size_t)b * NSAMP + T + tid] = 0.0f;
        out[(size_t)b * NSAMP + T + 256 + tid] = 0.0f;
        return;
    }
    __shared__ short tapsL[64 * 128];
    __shared__ short wsh[8][640];
    __shared__ float wf[640];
    __shared__ float ampf[4][128];
    __shared__ float vfL[64][4];
    __shared__ double PL[64][3];
    __shared__ float invnL[64];
    __shared__ float part[4][520];

    int tile2 = blockIdx.x * 2, s0 = tile2 - 1;
    for (int i = tid; i < 640; i += 256)
        wf[i] = noise[(size_t)b * NSAMP + ((T - 127 + i) & NMASK)] * 2.0f - 1.0f;
    {
        const short8v* src = (const short8v*)(tapsA + ((size_t)b << 13));
        short8v* dst = (short8v*)tapsL;
        for (int i = tid; i < 1024; i += 256) dst[i] = src[i];
    }
    for (int idx = tid; idx < 512; idx += 256) {
        int d = idx >> 7, ch2 = idx & 127;
        int fr = min(max(tile2 - 1 + d, 0), 127);
        ampf[d][ch2] = ampT[(size_t)b * 16384 + fr * 128 + ch2];
    }
    {
        int h = tid >> 2, dd = tid & 3;  // 256 threads exactly
        vfL[h][dd] = vfreq[((size_t)(b * 64 + h)) * 128 + min(max(s0 + dd, 0), 127)];
    }
    if (tid < 192) {
        int h = tid / 3, dd = tid - h * 3;
        PL[h][dd] = Pws[((size_t)(b * 64 + h)) * 128 + min(max(s0 + dd, 0), 127)];
    }
    if (tid < 64) invnL[tid] = 1.0f / (__uint_as_float(maxb[b * 64 + tid]) + 1e-8f);
    __syncthreads();
    for (int idx = tid; idx < 640; idx += 256) {
        int c = idx >> 3, s = idx & 7;
        short8v v;
#pragma unroll
        for (int e = 0; e < 8; ++e) {
            int t = 8 * c + e + s; t = t < 640 ? t : 639;
            v[e] = (short)f2bf(wf[t]);
        }
        *(short8v*)&wsh[s][8 * (c ^ s)] = v;
    }
    __syncthreads();

    int lane = tid & 63, w = tid >> 6;
    int g = lane >> 4, col = lane & 15, s_l = lane & 7, b3 = (lane >> 3) & 1;
    short8v fa[4][4];
#pragma unroll
    for (int mt = 0; mt < 4; ++mt)
#pragma unroll
        for (int ks = 0; ks < 4; ++ks) {
            int row = 16 * mt + col;
            int ch = (4 * ks + g) ^ (row & 7);
            fa[mt][ks] = *(const short8v*)&tapsL[row * 128 + 8 * ch];
        }
    int shift = shiftb[b];
    for (int ntl = 0; ntl < 8; ++ntl) {
        int nt = w * 8 + ntl;
        short8v fb[4];
#pragma unroll
        for (int ks = 0; ks < 4; ++ks) {
            int t0 = 120 + 16 * nt - 32 * ks - 8 * g + 8 * b3;
            int ch = (t0 >> 3) ^ s_l;
            fb[ks] = *(const short8v*)&wsh[s_l][8 * ch];
        }
        f32x4 acc[4] = {{0,0,0,0},{0,0,0,0},{0,0,0,0},{0,0,0,0}};
#pragma unroll
        for (int ks = 0; ks < 4; ++ks)
#pragma unroll
            for (int mt = 0; mt < 4; ++mt)
                acc[mt] = __builtin_amdgcn_mfma_f32_16x16x32_bf16(fa[mt][ks], fb[ks], acc[mt], 0, 0, 0);

        int j = w * 128 + ntl * 16 + col;
        int t = T + j;
        float coords = ((float)t + 0.5f) * (1.0f / 256.0f) - 0.5f;
        coords = fminf(fmaxf(coords, 0.0f), 127.0f);
        float lof = floorf(coords);
        int lo = (int)lof; int hi = min(lo + 1, 127);
        float w1 = coords - lof, w0 = 1.0f - w1;
        int dlo = lo - (tile2 - 1), dhi = hi - (tile2 - 1);

        bool head = (t < 128), tail = (t >= 32640);
        int u = t - 128;
        int uc = min(max(u, 0), 32511);
        int dd = min(max((uc >> 8) - s0, 0), 2);
        double mp1 = (double)((uc & 255) + 1);
        double mp2 = mp1 * mp1;
        float psum = 0.0f;
#pragma unroll
        for (int mt = 0; mt < 4; ++mt)
#pragma unroll
            for (int q = 0; q < 4; ++q) {
                int h = 16 * mt + 4 * g + q;
                double p;
                if (head)      p = (double)(t + 1) * (double)vfL[h][1];
                else if (tail) p = PL[h][2] + (double)(t - 32639) * (double)vfL[h][3];
                else {
                    float vs = vfL[h][dd], vs1 = vfL[h][dd + 1];
                    double dv = (double)(vs1 - vs) * (1.0 / 512.0);
                    p = PL[h][dd] + mp1 * (double)vs + dv * mp2;
                }
                double rev = p * INV_2PI; rev -= floor(rev);
                float sv = __sinf((float)(rev * TWO_PI));
                float aA = ampf[dlo][h] * w0 + ampf[dhi][h] * w1;
                float aB = ampf[dlo][64 + h] * w0 + ampf[dhi][64 + h] * w1;
                psum += sv * aA + acc[mt][q] * invnL[h] * aB;
            }
        part[g][j] = psum;
    }
    __syncthreads();
#pragma unroll
    for (int rep = 0; rep < 2; ++rep) {
        int j2 = rep * 256 + tid;
        float r = part[0][j2] + part[1][j2] + part[2][j2] + part[3][j2];
        int pos = (T + j2 + shift) & NMASK;
        out[(size_t)b * NSAMP + pos] = r;
    }
}

extern "C" void kernel_launch(void* const* d_in, const int* in_sizes, int n_in,
                              void* d_out, int out_size, void* d_ws, size_t ws_size,
                              hipStream_t stream) {
    const float* x     = (const float*)d_in[0];
    const float* Wsw   = (const float*)d_in[1];
    const float* bsw   = (const float*)d_in[2];
    const float* Wf0   = (const float*)d_in[3];
    const float* bf0   = (const float*)d_in[4];
    const float* Wfv   = (const float*)d_in[5];
    const float* bfv   = (const float*)d_in[6];
    const float* Wamp  = (const float*)d_in[7];
    const float* bamp  = (const float*)d_in[8];
    const float* Wloc  = (const float*)d_in[9];
    const float* bloc  = (const float*)d_in[10];
    const float* usw   = (const float*)d_in[11];
    const float* uloc  = (const float*)d_in[12];
    const float* noise = (const float*)d_in[13];

    char* ws = (char*)d_ws;
    double*   Pws    = (double*)(ws + OFF_P);
    float*    vfreq  = (float*)(ws + OFF_V);
    unsigned short* tapsA = (unsigned short*)(ws + OFF_TA);
    float*    ampT   = (float*)(ws + OFF_A);
    unsigned* maxb   = (unsigned*)(ws + OFF_M);
    float*    swb    = (float*)(ws + OFF_SW);
    int*      shiftb = (int*)(ws + OFF_SH);
    float*    out    = (float*)d_out;

    hipMemsetAsync(maxb, 0, 2048 * sizeof(unsigned), stream);
    amp_kernel<<<dim3(64), 256, 0, stream>>>(x, Wamp, bamp, ampT);
    prep_kernel<<<dim3(32), 128, 0, stream>>>(x, Wsw, bsw, Wf0, bf0, Wfv, bfv, Wloc, bloc,
                                              usw, uloc, Pws, vfreq, tapsA, swb, shiftb);
    convmax_kernel<<<dim3(64, 32), 256, 0, stream>>>(noise, tapsA, swb, maxb);
    final_kernel<<<dim3(64, 32), 256, 0, stream>>>(noise, tapsA, Pws, vfreq, ampT, maxb,
                                                   swb, shiftb, out);
}

// Round 3
// 123.201 us; speedup vs baseline: 3.1028x; 1.3458x over previous
//
#include <hip/hip_runtime.h>
#include <math.h>

typedef __attribute__((ext_vector_type(8))) short short8v;   // 8 bf16 (4 VGPRs)
typedef __attribute__((ext_vector_type(4))) float f32x4;

namespace {
constexpr int NSAMP = 32768;
constexpr int NMASK = NSAMP - 1;
constexpr float MIN_F_F = (float)(30.0 / 11025.0);
constexpr float SPAN_F  = (float)(3000.0 / 11025.0 - 30.0 / 11025.0);
constexpr float PI_F    = 3.14159265358979323846f;
constexpr double TWO_PI  = 6.283185307179586476925287;
constexpr double INV_2PI = 0.159154943091895335768884;
constexpr float INV_SQRT_N = 0.00552427172801990295f; // 1/sqrt(32768)

// ws layout (bytes)
constexpr size_t OFF_PM = 0;                          // float PmodF [32][64][128]  1 MB (phase prefix mod 2pi)
constexpr size_t OFF_V  = OFF_PM + 32*64*128*4;       // float vfreq [32][64][128]  1 MB
constexpr size_t OFF_TA = OFF_V  + 32*64*128*4;       // u16   tapsA [32][64][128]  512 KB (bf16, reversed+swizzled)
constexpr size_t OFF_A  = OFF_TA + 32*64*128*2;       // float ampT  [32][128fr][128ch] 2 MB
constexpr size_t OFF_M  = OFF_A  + 32*128*128*4;      // uint  maxb  [2048]
constexpr size_t OFF_SW = OFF_M  + 2048*4;            // float swb   [32]
constexpr size_t OFF_SH = OFF_SW + 32*4;              // int   shiftb[32]
}

__device__ __forceinline__ float sigmoidf_(float z) { return 1.0f / (1.0f + expf(-z)); }
__device__ __forceinline__ float gumbelf_(float u) { return -logf(-logf(u + 1e-10f) + 1e-10f); }
__device__ __forceinline__ unsigned short f2bf(float f) {
    unsigned u = __float_as_uint(f);
    return (unsigned short)((u + 0x7FFFu + ((u >> 16) & 1u)) >> 16);
}

// ---------------- amp = (x @ W_amp + b_amp)^2 -> transposed [32][fr][ch] ----------------
__launch_bounds__(128)
__global__ void amp_kernel(const float* __restrict__ x, const float* __restrict__ Wamp,
                           const float* __restrict__ bamp, float* __restrict__ ampT) {
    int j = blockIdx.x * 128 + threadIdx.x;  // 0..16383 ; ch = j>>7, fr = j&127
    __shared__ float xs[32 * 128];
    for (int i = threadIdx.x; i < 32 * 128; i += 128) xs[i] = x[i];
    __syncthreads();
    float acc[32];
    float bj = bamp[j];
#pragma unroll
    for (int b = 0; b < 32; ++b) acc[b] = bj;
    for (int d = 0; d < 128; ++d) {
        float wv = Wamp[(size_t)d * 16384 + j];
#pragma unroll
        for (int b = 0; b < 32; ++b) acc[b] = fmaf(xs[b * 128 + d], wv, acc[b]);
    }
    int ch = j >> 7, fr = j & 127;
#pragma unroll
    for (int b = 0; b < 32; ++b) {
        float a = acc[b];
        ampT[(size_t)b * 16384 + fr * 128 + ch] = a * a;
    }
}

// ---------------- per-b prep: gates, f0, freq table, phase prefixes (mod 2pi), bf16 taps ----
__launch_bounds__(128)
__global__ void prep_kernel(const float* __restrict__ x,
                            const float* __restrict__ Wsw, const float* __restrict__ bsw,
                            const float* __restrict__ Wf0, const float* __restrict__ bf0,
                            const float* __restrict__ Wfv, const float* __restrict__ bfv,
                            const float* __restrict__ Wloc, const float* __restrict__ bloc,
                            const float* __restrict__ usw, const float* __restrict__ uloc,
                            float* __restrict__ PmodF, float* __restrict__ vfreq,
                            unsigned short* __restrict__ tapsA, float* __restrict__ swb,
                            int* __restrict__ shiftb) {
    int b = blockIdx.x, tid = threadIdx.x;  // 128 threads
    __shared__ float xs[128], f0t[128];
    __shared__ float redA[128]; __shared__ int redI[128];
    __shared__ float red0[128], red1[128], red2[128];
    xs[tid] = x[b * 128 + tid];
    __syncthreads();

    float aFv = bfv[tid], aLoc = bloc[tid];
    for (int d = 0; d < 128; ++d) {
        float xv = xs[d];
        aFv  = fmaf(xv, Wfv[d * 128 + tid], aFv);
        aLoc = fmaf(xv, Wloc[d * 128 + tid], aLoc);
    }
    float f0var = sigmoidf_(aFv) * 2.0f - 1.0f;
    float yloc = sigmoidf_(aLoc) + gumbelf_(uloc[b * 128 + tid]);

    redA[tid] = yloc; redI[tid] = tid;
    __syncthreads();
    for (int off = 64; off > 0; off >>= 1) {
        if (tid < off) {
            if (redA[tid + off] > redA[tid]) { redA[tid] = redA[tid + off]; redI[tid] = redI[tid + off]; }
        }
        __syncthreads();
    }
    int frame = redI[0];

    red0[tid] = xs[tid] * Wsw[tid * 2 + 0];
    red1[tid] = xs[tid] * Wsw[tid * 2 + 1];
    red2[tid] = xs[tid] * Wf0[tid];
    __syncthreads();
    for (int off = 64; off > 0; off >>= 1) {
        if (tid < off) { red0[tid] += red0[tid + off]; red1[tid] += red1[tid + off]; red2[tid] += red2[tid + off]; }
        __syncthreads();
    }
    float l0 = red0[0] + bsw[0], l1 = red1[0] + bsw[1];
    float g0 = gumbelf_(usw[b * 2 + 0]), g1 = gumbelf_(usw[b * 2 + 1]);
    float swv = (l0 + g0 >= l1 + g1) ? 1.0f : 0.0f;
    float sg = sigmoidf_(red2[0] + bf0[0]);
    float f0v = MIN_F_F + (sg * sg) * SPAN_F;
    if (tid == 0) { swb[b] = swv; shiftb[b] = frame * 256; }

    f0t[tid] = f0v + f0var * (f0v * 0.01f);
    __syncthreads();

    if (tid < 64) {
        int h = tid;
        float hf = (float)(h + 1);
        size_t base = ((size_t)b * 64 + h) * 128;
        double P = 0.0;
        float vprev = 0.0f, v0 = 0.0f;
        for (int k = 0; k < 128; ++k) {
            float v = f0t[k] * hf;
            v = (v > 1.0f) ? 0.0f : v * PI_F;
            vfreq[base + k] = v;
            if (k == 0) { v0 = v; P = 128.0 * (double)v; }
            else        { P += 128.0 * ((double)vprev + (double)v); }
            double rev = P * INV_2PI; rev -= floor(rev);
            PmodF[base + k] = (float)(rev * TWO_PI);   // prefix phase at segment-k start, mod 2pi
            vprev = v;
        }
        // taps, bf16, reversed within 8-groups + 16B-chunk XOR swizzle by (h&7)
        double v0rev = (double)v0 * INV_2PI;
        for (int k = 0; k < 128; ++k) {
            float hwk = 0.54f - 0.46f * cosf(6.2831853071795864769f * (float)k / 128.0f);
            double rv = (double)(k + 1) * v0rev; rv -= floor(rv);
            float sv = __sinf((float)(rv * TWO_PI));
            float tv = sv * hwk * INV_SQRT_N;
            int c = k >> 3, e = 7 - (k & 7);
            tapsA[base + 8 * (c ^ (h & 7)) + e] = f2bf(tv);
        }
    }
}

// Conv core notes:
//   k-fill convention (same for A and B, so any HW k-permutation cancels):
//     frag[r] corresponds to logical k = 32*ks + 8*(lane>>4) + (7 - r)
//   A (taps) stored pre-reversed -> one aligned b128 per (mt,ks)
//   B: wsh[s][t] = w[t+s], chunk c stored at c^s -> one aligned, conflict-free b128

// ---------------- pass 1: MFMA circular FIR, per-(b,h) row max ----------------
__launch_bounds__(256)
__global__ void convmax_kernel(const float* __restrict__ noise,
                               const unsigned short* __restrict__ tapsA,
                               const float* __restrict__ swb,
                               unsigned int* __restrict__ maxb) {
    int b = blockIdx.y;
    if (swb[b] == 0.0f) return;
    int T = blockIdx.x * 512, tid = threadIdx.x;
    __shared__ short tapsL[64 * 128];
    __shared__ short wsh[8][640];
    __shared__ float wf[640];
    __shared__ unsigned maxL[64];
    if (tid < 64) maxL[tid] = 0u;
    for (int i = tid; i < 640; i += 256)
        wf[i] = noise[(size_t)b * NSAMP + ((T - 127 + i) & NMASK)] * 2.0f - 1.0f;
    {
        const short8v* src = (const short8v*)(tapsA + ((size_t)b << 13));
        short8v* dst = (short8v*)tapsL;
        for (int i = tid; i < 1024; i += 256) dst[i] = src[i];
    }
    __syncthreads();
    for (int idx = tid; idx < 640; idx += 256) {
        int c = idx >> 3, s = idx & 7;
        short8v v;
#pragma unroll
        for (int e = 0; e < 8; ++e) {
            int t = 8 * c + e + s; t = t < 640 ? t : 639;
            v[e] = (short)f2bf(wf[t]);
        }
        *(short8v*)&wsh[s][8 * (c ^ s)] = v;
    }
    __syncthreads();
    int lane = tid & 63, w = tid >> 6;
    int g = lane >> 4, col = lane & 15, s_l = lane & 7, b3 = (lane >> 3) & 1;
    short8v fa[4][4];
#pragma unroll
    for (int mt = 0; mt < 4; ++mt)
#pragma unroll
        for (int ks = 0; ks < 4; ++ks) {
            int row = 16 * mt + col;
            int ch = (4 * ks + g) ^ (row & 7);
            fa[mt][ks] = *(const short8v*)&tapsL[row * 128 + 8 * ch];
        }
    float rm[4][4];
#pragma unroll
    for (int mt = 0; mt < 4; ++mt)
#pragma unroll
        for (int q = 0; q < 4; ++q) rm[mt][q] = 0.0f;
    for (int ntl = 0; ntl < 8; ++ntl) {
        int nt = w * 8 + ntl;
        short8v fb[4];
#pragma unroll
        for (int ks = 0; ks < 4; ++ks) {
            int t0 = 120 + 16 * nt - 32 * ks - 8 * g + 8 * b3;
            int ch = (t0 >> 3) ^ s_l;
            fb[ks] = *(const short8v*)&wsh[s_l][8 * ch];
        }
        f32x4 acc[4] = {{0,0,0,0},{0,0,0,0},{0,0,0,0},{0,0,0,0}};
#pragma unroll
        for (int ks = 0; ks < 4; ++ks)
#pragma unroll
            for (int mt = 0; mt < 4; ++mt)
                acc[mt] = __builtin_amdgcn_mfma_f32_16x16x32_bf16(fa[mt][ks], fb[ks], acc[mt], 0, 0, 0);
#pragma unroll
        for (int mt = 0; mt < 4; ++mt)
#pragma unroll
            for (int q = 0; q < 4; ++q) rm[mt][q] = fmaxf(rm[mt][q], fabsf(acc[mt][q]));
    }
#pragma unroll
    for (int mt = 0; mt < 4; ++mt)
#pragma unroll
        for (int q = 0; q < 4; ++q) {
            float m = rm[mt][q];
            m = fmaxf(m, __shfl_xor(m, 1));
            m = fmaxf(m, __shfl_xor(m, 2));
            m = fmaxf(m, __shfl_xor(m, 4));
            m = fmaxf(m, __shfl_xor(m, 8));
            if (col == 0) atomicMax(&maxL[16 * mt + 4 * g + q], __float_as_uint(m));
        }
    __syncthreads();
    if (tid < 64) atomicMax(&maxb[b * 64 + tid], maxL[tid]);
}

// ---------------- pass 2: fused MFMA conv + f32 closed-form sine + amp lerp + reduce + shift ----
__launch_bounds__(256)
__global__ void final_kernel(const float* __restrict__ noise,
                             const unsigned short* __restrict__ tapsA,
                             const float* __restrict__ PmodF, const float* __restrict__ vfreq,
                             const float* __restrict__ ampT,
                             const unsigned int* __restrict__ maxb,
                             const float* __restrict__ swb, const int* __restrict__ shiftb,
                             float* __restrict__ out) {
    int b = blockIdx.y;
    int T = blockIdx.x * 512, tid = threadIdx.x;
    if (swb[b] == 0.0f) {
        out[(size_t)b * NSAMP + T + tid] = 0.0f;
        out[(size_t)b * NSAMP + T + 256 + tid] = 0.0f;
        return;
    }
    // tapsL is only read before the main loop (fa fragments); part is only
    // written after the post-staging barrier -> safe to union them.
    __shared__ union { short tapsL[64 * 128]; float part[4][520]; } R;
    __shared__ short wsh[8][640];
    __shared__ float wf[640];
    __shared__ float4 seg[3][64];    // (vs, dv, Pb mod 2pi, invn) per (segment-slot, h)
    __shared__ float2 ampf2[4][64];  // (ampA, ampB) per (frame-slot, h)

    int tile2 = blockIdx.x * 2, s0 = tile2 - 1;
    for (int i = tid; i < 640; i += 256)
        wf[i] = noise[(size_t)b * NSAMP + ((T - 127 + i) & NMASK)] * 2.0f - 1.0f;
    {
        const short8v* src = (const short8v*)(tapsA + ((size_t)b << 13));
        short8v* dst = (short8v*)R.tapsL;
        for (int i = tid; i < 1024; i += 256) dst[i] = src[i];
    }
    {
        int d = tid >> 6, h2 = tid & 63;
        int fr = min(max(s0 + d, 0), 127);
        float2 a;
        a.x = ampT[(size_t)b * 16384 + fr * 128 + h2];
        a.y = ampT[(size_t)b * 16384 + fr * 128 + 64 + h2];
        ampf2[d][h2] = a;
    }
    if (tid < 192) {
        int dd = tid >> 6, h2 = tid & 63;
        size_t vb = ((size_t)(b * 64 + h2)) * 128;
        int s = min(max(s0 + dd, 0), 127), s1 = min(s + 1, 127);
        float vs = vfreq[vb + s], vs1 = vfreq[vb + s1];
        float4 sgv;
        sgv.x = vs;
        sgv.y = (vs1 - vs) * (1.0f / 512.0f);
        sgv.z = PmodF[vb + s];
        sgv.w = 1.0f / (__uint_as_float(maxb[b * 64 + h2]) + 1e-8f);
        seg[dd][h2] = sgv;
    }
    __syncthreads();
    for (int idx = tid; idx < 640; idx += 256) {
        int c = idx >> 3, s = idx & 7;
        short8v v;
#pragma unroll
        for (int e = 0; e < 8; ++e) {
            int t = 8 * c + e + s; t = t < 640 ? t : 639;
            v[e] = (short)f2bf(wf[t]);
        }
        *(short8v*)&wsh[s][8 * (c ^ s)] = v;
    }
    int lane = tid & 63, w = tid >> 6;
    int g = lane >> 4, col = lane & 15, s_l = lane & 7, b3 = (lane >> 3) & 1;
    short8v fa[4][4];
#pragma unroll
    for (int mt = 0; mt < 4; ++mt)
#pragma unroll
        for (int ks = 0; ks < 4; ++ks) {
            int row = 16 * mt + col;
            int ch = (4 * ks + g) ^ (row & 7);
            fa[mt][ks] = *(const short8v*)&R.tapsL[row * 128 + 8 * ch];
        }
    __syncthreads();

    int dd = (w + 1) >> 1;                 // per-thread constant segment slot {0,1,1,2}
    bool head = (T + w * 128) < 128;       // only block 0, w==0
    int shift = shiftb[b];
    for (int ntl = 0; ntl < 8; ++ntl) {
        int nt = w * 8 + ntl;
        short8v fb[4];
#pragma unroll
        for (int ks = 0; ks < 4; ++ks) {
            int t0 = 120 + 16 * nt - 32 * ks - 8 * g + 8 * b3;
            int ch = (t0 >> 3) ^ s_l;
            fb[ks] = *(const short8v*)&wsh[s_l][8 * ch];
        }
        f32x4 acc[4] = {{0,0,0,0},{0,0,0,0},{0,0,0,0},{0,0,0,0}};
#pragma unroll
        for (int ks = 0; ks < 4; ++ks)
#pragma unroll
            for (int mt = 0; mt < 4; ++mt)
                acc[mt] = __builtin_amdgcn_mfma_f32_16x16x32_bf16(fa[mt][ks], fb[ks], acc[mt], 0, 0, 0);

        int j = w * 128 + ntl * 16 + col;
        int t = T + j;
        float coords = ((float)t + 0.5f) * (1.0f / 256.0f) - 0.5f;
        coords = fminf(fmaxf(coords, 0.0f), 127.0f);
        float lof = floorf(coords);
        int lo = (int)lof; int hi = min(lo + 1, 127);
        float w1 = coords - lof;
        int dlo = lo - s0, dhi = hi - s0;
        int m = ((t - 128) & 255) + 1;
        float mp1 = (float)m, mp2 = mp1 * mp1;
        float tp1 = (float)(t + 1);
        float psum = 0.0f;
#pragma unroll
        for (int mt = 0; mt < 4; ++mt)
#pragma unroll
            for (int q = 0; q < 4; ++q) {
                int h = 16 * mt + 4 * g + q;
                float4 sgv = seg[dd][h];
                float p = head ? tp1 * sgv.x
                               : fmaf(mp2, sgv.y, fmaf(mp1, sgv.x, sgv.z));
                float sv = __sinf(p);
                float2 alo = ampf2[dlo][h], ahi = ampf2[dhi][h];
                float aA = fmaf(w1, ahi.x - alo.x, alo.x);
                float aB = fmaf(w1, ahi.y - alo.y, alo.y);
                psum = fmaf(sv, aA, psum);
                psum = fmaf(acc[mt][q] * sgv.w, aB, psum);
            }
        R.part[g][j] = psum;
    }
    __syncthreads();
#pragma unroll
    for (int rep = 0; rep < 2; ++rep) {
        int j2 = rep * 256 + tid;
        float r = R.part[0][j2] + R.part[1][j2] + R.part[2][j2] + R.part[3][j2];
        int pos = (T + j2 + shift) & NMASK;
        out[(size_t)b * NSAMP + pos] = r;
    }
}

extern "C" void kernel_launch(void* const* d_in, const int* in_sizes, int n_in,
                              void* d_out, int out_size, void* d_ws, size_t ws_size,
                              hipStream_t stream) {
    const float* x     = (const float*)d_in[0];
    const float* Wsw   = (const float*)d_in[1];
    const float* bsw   = (const float*)d_in[2];
    const float* Wf0   = (const float*)d_in[3];
    const float* bf0   = (const float*)d_in[4];
    const float* Wfv   = (const float*)d_in[5];
    const float* bfv   = (const float*)d_in[6];
    const float* Wamp  = (const float*)d_in[7];
    const float* bamp  = (const float*)d_in[8];
    const float* Wloc  = (const float*)d_in[9];
    const float* bloc  = (const float*)d_in[10];
    const float* usw   = (const float*)d_in[11];
    const float* uloc  = (const float*)d_in[12];
    const float* noise = (const float*)d_in[13];

    char* ws = (char*)d_ws;
    float*    PmodF  = (float*)(ws + OFF_PM);
    float*    vfreq  = (float*)(ws + OFF_V);
    unsigned short* tapsA = (unsigned short*)(ws + OFF_TA);
    float*    ampT   = (float*)(ws + OFF_A);
    unsigned* maxb   = (unsigned*)(ws + OFF_M);
    float*    swb    = (float*)(ws + OFF_SW);
    int*      shiftb = (int*)(ws + OFF_SH);
    float*    out    = (float*)d_out;

    hipMemsetAsync(maxb, 0, 2048 * sizeof(unsigned), stream);
    amp_kernel<<<dim3(128), 128, 0, stream>>>(x, Wamp, bamp, ampT);
    prep_kernel<<<dim3(32), 128, 0, stream>>>(x, Wsw, bsw, Wf0, bf0, Wfv, bfv, Wloc, bloc,
                                              usw, uloc, PmodF, vfreq, tapsA, swb, shiftb);
    convmax_kernel<<<dim3(64, 32), 256, 0, stream>>>(noise, tapsA, swb, maxb);
    final_kernel<<<dim3(64, 32), 256, 0, stream>>>(noise, tapsA, PmodF, vfreq, ampT, maxb,
                                                   swb, shiftb, out);
}

// Round 4
// 92.543 us; speedup vs baseline: 4.1307x; 1.3313x over previous
//
#include <hip/hip_runtime.h>
#include <math.h>

typedef __attribute__((ext_vector_type(8))) short short8v;   // 8 bf16 (4 VGPRs)
typedef __attribute__((ext_vector_type(4))) float f32x4;

namespace {
constexpr int NSAMP = 32768;
constexpr int NMASK = NSAMP - 1;
constexpr float MIN_F_F = (float)(30.0 / 11025.0);
constexpr float SPAN_F  = (float)(3000.0 / 11025.0 - 30.0 / 11025.0);
constexpr float PI_F    = 3.14159265358979323846f;
constexpr double TWO_PI  = 6.283185307179586476925287;
constexpr double INV_2PI = 0.159154943091895335768884;
constexpr float INV_SQRT_N = 0.00552427172801990295f; // 1/sqrt(32768)

// ws layout (bytes)
constexpr size_t OFF_PM = 0;                          // float PmodF [32][64][128]  1 MB (phase prefix mod 2pi)
constexpr size_t OFF_V  = OFF_PM + 32*64*128*4;       // float vfreq [32][64][128]  1 MB
constexpr size_t OFF_TA = OFF_V  + 32*64*128*4;       // u16   tapsA [32][64][128]  512 KB (bf16, reversed+swizzled)
constexpr size_t OFF_A  = OFF_TA + 32*64*128*2;       // float ampT  [32][128fr][128ch] 2 MB
constexpr size_t OFF_M  = OFF_A  + 32*128*128*4;      // uint  maxb  [2048]
constexpr size_t OFF_SW = OFF_M  + 2048*4;            // float swb   [32]
constexpr size_t OFF_SH = OFF_SW + 32*4;              // int   shiftb[32]
}

__device__ __forceinline__ float sigmoidf_(float z) { return 1.0f / (1.0f + expf(-z)); }
__device__ __forceinline__ float gumbelf_(float u) { return -logf(-logf(u + 1e-10f) + 1e-10f); }
__device__ __forceinline__ unsigned short f2bf(float f) {
    unsigned u = __float_as_uint(f);
    return (unsigned short)((u + 0x7FFFu + ((u >> 16) & 1u)) >> 16);
}

// ---------------- amp = (x @ W_amp + b_amp)^2 -> transposed [32][fr][ch] ----------------
// 512 blocks x 128 thr: bq = b-quadrant (8 b's), jt = 128-wide j tile.
// x reads are wave-uniform (scalar s_load path); Wamp loads coalesced, unroll-8 for MLP.
__launch_bounds__(128)
__global__ void amp_kernel(const float* __restrict__ x, const float* __restrict__ Wamp,
                           const float* __restrict__ bamp, float* __restrict__ ampT) {
    int blk = blockIdx.x;
    int bq = blk >> 7;              // 0..3
    int jt = blk & 127;
    int tid = threadIdx.x;
    int j = jt * 128 + tid;
    float acc[8];
    float bj = bamp[j];
#pragma unroll
    for (int b = 0; b < 8; ++b) acc[b] = bj;
    const float* xb = x + bq * 8 * 128;
#pragma unroll 8
    for (int d = 0; d < 128; ++d) {
        float wv = Wamp[(size_t)d * 16384 + j];
#pragma unroll
        for (int b = 0; b < 8; ++b) acc[b] = fmaf(xb[b * 128 + d], wv, acc[b]);
    }
    int ch = j >> 7, fr = j & 127;  // ch == jt, fr == tid
#pragma unroll
    for (int b = 0; b < 8; ++b) {
        float a = acc[b];
        ampT[(size_t)(bq * 8 + b) * 16384 + fr * 128 + ch] = a * a;
    }
}

// ---------------- per-b prep: gates, f0, freq table, phase prefixes (mod 2pi), bf16 taps ----
__launch_bounds__(128)
__global__ void prep_kernel(const float* __restrict__ x,
                            const float* __restrict__ Wsw, const float* __restrict__ bsw,
                            const float* __restrict__ Wf0, const float* __restrict__ bf0,
                            const float* __restrict__ Wfv, const float* __restrict__ bfv,
                            const float* __restrict__ Wloc, const float* __restrict__ bloc,
                            const float* __restrict__ usw, const float* __restrict__ uloc,
                            float* __restrict__ PmodF, float* __restrict__ vfreq,
                            unsigned short* __restrict__ tapsA, float* __restrict__ swb,
                            int* __restrict__ shiftb, unsigned int* __restrict__ maxb) {
    int b = blockIdx.x, tid = threadIdx.x;  // 128 threads
    __shared__ float xs[128], f0t[128];
    __shared__ float redA[128]; __shared__ int redI[128];
    __shared__ float red0[128], red1[128], red2[128];
    if (tid < 64) maxb[b * 64 + tid] = 0u;   // replaces hipMemsetAsync (prep precedes convmax on-stream)
    xs[tid] = x[b * 128 + tid];
    __syncthreads();

    float aFv = bfv[tid], aLoc = bloc[tid];
    for (int d = 0; d < 128; ++d) {
        float xv = xs[d];
        aFv  = fmaf(xv, Wfv[d * 128 + tid], aFv);
        aLoc = fmaf(xv, Wloc[d * 128 + tid], aLoc);
    }
    float f0var = sigmoidf_(aFv) * 2.0f - 1.0f;
    float yloc = sigmoidf_(aLoc) + gumbelf_(uloc[b * 128 + tid]);

    redA[tid] = yloc; redI[tid] = tid;
    __syncthreads();
    for (int off = 64; off > 0; off >>= 1) {
        if (tid < off) {
            if (redA[tid + off] > redA[tid]) { redA[tid] = redA[tid + off]; redI[tid] = redI[tid + off]; }
        }
        __syncthreads();
    }
    int frame = redI[0];

    red0[tid] = xs[tid] * Wsw[tid * 2 + 0];
    red1[tid] = xs[tid] * Wsw[tid * 2 + 1];
    red2[tid] = xs[tid] * Wf0[tid];
    __syncthreads();
    for (int off = 64; off > 0; off >>= 1) {
        if (tid < off) { red0[tid] += red0[tid + off]; red1[tid] += red1[tid + off]; red2[tid] += red2[tid + off]; }
        __syncthreads();
    }
    float l0 = red0[0] + bsw[0], l1 = red1[0] + bsw[1];
    float g0 = gumbelf_(usw[b * 2 + 0]), g1 = gumbelf_(usw[b * 2 + 1]);
    float swv = (l0 + g0 >= l1 + g1) ? 1.0f : 0.0f;
    float sg = sigmoidf_(red2[0] + bf0[0]);
    float f0v = MIN_F_F + (sg * sg) * SPAN_F;
    if (tid == 0) { swb[b] = swv; shiftb[b] = frame * 256; }

    f0t[tid] = f0v + f0var * (f0v * 0.01f);
    __syncthreads();

    if (tid < 64) {
        int h = tid;
        float hf = (float)(h + 1);
        size_t base = ((size_t)b * 64 + h) * 128;
        double P = 0.0;
        float vprev = 0.0f, v0 = 0.0f;
        for (int k = 0; k < 128; ++k) {
            float v = f0t[k] * hf;
            v = (v > 1.0f) ? 0.0f : v * PI_F;
            vfreq[base + k] = v;
            if (k == 0) { v0 = v; P = 128.0 * (double)v; }
            else        { P += 128.0 * ((double)vprev + (double)v); }
            double rev = P * INV_2PI; rev -= floor(rev);
            PmodF[base + k] = (float)(rev * TWO_PI);   // prefix phase at segment-k start, mod 2pi
            vprev = v;
        }
        // taps, bf16, reversed within 8-groups + 16B-chunk XOR swizzle by (h&7)
        double v0rev = (double)v0 * INV_2PI;
        for (int k = 0; k < 128; ++k) {
            float hwk = 0.54f - 0.46f * cosf(6.2831853071795864769f * (float)k / 128.0f);
            double rv = (double)(k + 1) * v0rev; rv -= floor(rv);
            float sv = __sinf((float)(rv * TWO_PI));
            float tv = sv * hwk * INV_SQRT_N;
            int c = k >> 3, e = 7 - (k & 7);
            tapsA[base + 8 * (c ^ (h & 7)) + e] = f2bf(tv);
        }
    }
}

// Conv core notes:
//   k-fill convention (same for A and B, so any HW k-permutation cancels):
//     frag[r] corresponds to logical k = 32*ks + 8*(lane>>4) + (7 - r)
//   A (taps) stored pre-reversed -> one aligned b128 per (mt,ks)
//   B: wsh[s][t] = w[t+s], chunk c stored at c^s -> one aligned, conflict-free b128

// ---------------- pass 1: MFMA circular FIR, per-(b,h) row max ----------------
__launch_bounds__(256)
__global__ void convmax_kernel(const float* __restrict__ noise,
                               const unsigned short* __restrict__ tapsA,
                               const float* __restrict__ swb,
                               unsigned int* __restrict__ maxb) {
    int b = blockIdx.y;
    if (swb[b] == 0.0f) return;
    int T = blockIdx.x * 512, tid = threadIdx.x;
    __shared__ short tapsL[64 * 128];
    __shared__ short wsh[8][640];
    __shared__ float wf[640];
    __shared__ unsigned maxL[64];
    if (tid < 64) maxL[tid] = 0u;
    for (int i = tid; i < 640; i += 256)
        wf[i] = noise[(size_t)b * NSAMP + ((T - 127 + i) & NMASK)] * 2.0f - 1.0f;
    {
        const short8v* src = (const short8v*)(tapsA + ((size_t)b << 13));
        short8v* dst = (short8v*)tapsL;
        for (int i = tid; i < 1024; i += 256) dst[i] = src[i];
    }
    __syncthreads();
    for (int idx = tid; idx < 640; idx += 256) {
        int c = idx >> 3, s = idx & 7;
        short8v v;
#pragma unroll
        for (int e = 0; e < 8; ++e) {
            int t = 8 * c + e + s; t = t < 640 ? t : 639;
            v[e] = (short)f2bf(wf[t]);
        }
        *(short8v*)&wsh[s][8 * (c ^ s)] = v;
    }
    __syncthreads();
    int lane = tid & 63, w = tid >> 6;
    int g = lane >> 4, col = lane & 15, s_l = lane & 7, b3 = (lane >> 3) & 1;
    short8v fa[4][4];
#pragma unroll
    for (int mt = 0; mt < 4; ++mt)
#pragma unroll
        for (int ks = 0; ks < 4; ++ks) {
            int row = 16 * mt + col;
            int ch = (4 * ks + g) ^ (row & 7);
            fa[mt][ks] = *(const short8v*)&tapsL[row * 128 + 8 * ch];
        }
    float rm[4][4];
#pragma unroll
    for (int mt = 0; mt < 4; ++mt)
#pragma unroll
        for (int q = 0; q < 4; ++q) rm[mt][q] = 0.0f;
    for (int ntl = 0; ntl < 8; ++ntl) {
        int nt = w * 8 + ntl;
        short8v fb[4];
#pragma unroll
        for (int ks = 0; ks < 4; ++ks) {
            int t0 = 120 + 16 * nt - 32 * ks - 8 * g + 8 * b3;
            int ch = (t0 >> 3) ^ s_l;
            fb[ks] = *(const short8v*)&wsh[s_l][8 * ch];
        }
        f32x4 acc[4] = {{0,0,0,0},{0,0,0,0},{0,0,0,0},{0,0,0,0}};
#pragma unroll
        for (int ks = 0; ks < 4; ++ks)
#pragma unroll
            for (int mt = 0; mt < 4; ++mt)
                acc[mt] = __builtin_amdgcn_mfma_f32_16x16x32_bf16(fa[mt][ks], fb[ks], acc[mt], 0, 0, 0);
#pragma unroll
        for (int mt = 0; mt < 4; ++mt)
#pragma unroll
            for (int q = 0; q < 4; ++q) rm[mt][q] = fmaxf(rm[mt][q], fabsf(acc[mt][q]));
    }
#pragma unroll
    for (int mt = 0; mt < 4; ++mt)
#pragma unroll
        for (int q = 0; q < 4; ++q) {
            float m = rm[mt][q];
            m = fmaxf(m, __shfl_xor(m, 1));
            m = fmaxf(m, __shfl_xor(m, 2));
            m = fmaxf(m, __shfl_xor(m, 4));
            m = fmaxf(m, __shfl_xor(m, 8));
            if (col == 0) atomicMax(&maxL[16 * mt + 4 * g + q], __float_as_uint(m));
        }
    __syncthreads();
    if (tid < 64) atomicMax(&maxb[b * 64 + tid], maxL[tid]);
}

// ---------------- pass 2: fused MFMA conv + f32 closed-form sine + amp lerp + reduce + shift ----
__launch_bounds__(256)
__global__ void final_kernel(const float* __restrict__ noise,
                             const unsigned short* __restrict__ tapsA,
                             const float* __restrict__ PmodF, const float* __restrict__ vfreq,
                             const float* __restrict__ ampT,
                             const unsigned int* __restrict__ maxb,
                             const float* __restrict__ swb, const int* __restrict__ shiftb,
                             float* __restrict__ out) {
    int b = blockIdx.y;
    int T = blockIdx.x * 512, tid = threadIdx.x;
    if (swb[b] == 0.0f) {
        out[(size_t)b * NSAMP + T + tid] = 0.0f;
        out[(size_t)b * NSAMP + T + 256 + tid] = 0.0f;
        return;
    }
    // tapsL read only before the main loop (fa fragments); part written only
    // after the post-staging barrier -> safe to union.
    __shared__ union { short tapsL[64 * 128]; float part[4][520]; } R;
    __shared__ short wsh[8][640];
    __shared__ float wf[640];
    __shared__ float4 seg[3][64];    // (vs, dv, Pb mod 2pi, -) per (segment-slot, h)
    __shared__ float invnL[64];
    __shared__ float2 ampf2[4][64];  // (ampA, ampB*invn) per (frame-slot, h)

    int tile2 = blockIdx.x * 2, s0 = tile2 - 1;
    // ---- phase A: global loads ----
    for (int i = tid; i < 640; i += 256)
        wf[i] = noise[(size_t)b * NSAMP + ((T - 127 + i) & NMASK)] * 2.0f - 1.0f;
    {
        const short8v* src = (const short8v*)(tapsA + ((size_t)b << 13));
        short8v* dst = (short8v*)R.tapsL;
        for (int i = tid; i < 1024; i += 256) dst[i] = src[i];
    }
    int ad = tid >> 6, ah = tid & 63;
    int afr = min(max(s0 + ad, 0), 127);
    float ampA_r = ampT[(size_t)b * 16384 + afr * 128 + ah];
    float ampB_r = ampT[(size_t)b * 16384 + afr * 128 + 64 + ah];
    if (tid < 192) {
        int dd = tid >> 6, h2 = tid & 63;
        size_t vb = ((size_t)(b * 64 + h2)) * 128;
        int s = min(max(s0 + dd, 0), 127), s1 = min(s + 1, 127);
        float vs = vfreq[vb + s], vs1 = vfreq[vb + s1];
        float4 sgv;
        sgv.x = vs;
        sgv.y = (vs1 - vs) * (1.0f / 512.0f);
        sgv.z = PmodF[vb + s];
        sgv.w = 0.0f;
        seg[dd][h2] = sgv;
    }
    if (tid < 64) invnL[tid] = 1.0f / (__uint_as_float(maxb[b * 64 + tid]) + 1e-8f);
    __syncthreads();
    // ---- phase B: LDS->LDS builds + fragment/seg hoists ----
    {
        float2 a; a.x = ampA_r; a.y = ampB_r * invnL[ah];
        ampf2[ad][ah] = a;
    }
    for (int idx = tid; idx < 640; idx += 256) {
        int c = idx >> 3, s = idx & 7;
        short8v v;
#pragma unroll
        for (int e = 0; e < 8; ++e) {
            int t = 8 * c + e + s; t = t < 640 ? t : 639;
            v[e] = (short)f2bf(wf[t]);
        }
        *(short8v*)&wsh[s][8 * (c ^ s)] = v;
    }
    int lane = tid & 63, w = tid >> 6;
    int g = lane >> 4, col = lane & 15, s_l = lane & 7, b3 = (lane >> 3) & 1;
    short8v fa[4][4];
#pragma unroll
    for (int mt = 0; mt < 4; ++mt)
#pragma unroll
        for (int ks = 0; ks < 4; ++ks) {
            int row = 16 * mt + col;
            int ch = (4 * ks + g) ^ (row & 7);
            fa[mt][ks] = *(const short8v*)&R.tapsL[row * 128 + 8 * ch];
        }
    int dd = (w + 1) >> 1;                 // per-thread constant segment slot {0,1,1,2}
    bool head = (T + w * 128) < 128;       // only block 0, w==0
    float vsr[16], dvr[16], pbr[16];
#pragma unroll
    for (int mt = 0; mt < 4; ++mt)
#pragma unroll
        for (int q = 0; q < 4; ++q) {
            int i = mt * 4 + q, h = 16 * mt + 4 * g + q;
            float4 sgv = seg[dd][h];
            vsr[i] = sgv.x;
            dvr[i] = head ? 0.0f : sgv.y;
            pbr[i] = head ? (-128.0f * sgv.x) : sgv.z;   // head: p=(t+1)*v0 with m=t+129
        }
    __syncthreads();

    int shift = shiftb[b];
    for (int ntl = 0; ntl < 8; ++ntl) {
        int nt = w * 8 + ntl;
        short8v fb[4];
#pragma unroll
        for (int ks = 0; ks < 4; ++ks) {
            int t0 = 120 + 16 * nt - 32 * ks - 8 * g + 8 * b3;
            int ch = (t0 >> 3) ^ s_l;
            fb[ks] = *(const short8v*)&wsh[s_l][8 * ch];
        }
        f32x4 acc[4] = {{0,0,0,0},{0,0,0,0},{0,0,0,0},{0,0,0,0}};
#pragma unroll
        for (int ks = 0; ks < 4; ++ks)
#pragma unroll
            for (int mt = 0; mt < 4; ++mt)
                acc[mt] = __builtin_amdgcn_mfma_f32_16x16x32_bf16(fa[mt][ks], fb[ks], acc[mt], 0, 0, 0);

        int j = w * 128 + ntl * 16 + col;
        int t = T + j;
        float coords = ((float)t + 0.5f) * (1.0f / 256.0f) - 0.5f;
        coords = fminf(fmaxf(coords, 0.0f), 127.0f);
        float lof = floorf(coords);
        int lo = (int)lof; int hi = min(lo + 1, 127);
        float w1 = coords - lof;
        int dlo = lo - s0, dhi = hi - s0;
        float mp1 = (float)(((t - 128) & 255) + 1);
        float mp2 = mp1 * mp1;
        float psum = 0.0f;
#pragma unroll
        for (int mt = 0; mt < 4; ++mt)
#pragma unroll
            for (int q = 0; q < 4; ++q) {
                int i = mt * 4 + q, h = 16 * mt + 4 * g + q;
                float p = fmaf(mp2, dvr[i], fmaf(mp1, vsr[i], pbr[i]));
                float sv = __sinf(p);
                float2 alo = ampf2[dlo][h], ahi = ampf2[dhi][h];
                float aA = fmaf(w1, ahi.x - alo.x, alo.x);
                float aB = fmaf(w1, ahi.y - alo.y, alo.y);
                psum = fmaf(sv, aA, psum);
                psum = fmaf(acc[mt][q], aB, psum);
            }
        R.part[g][j] = psum;
    }
    __syncthreads();
#pragma unroll
    for (int rep = 0; rep < 2; ++rep) {
        int j2 = rep * 256 + tid;
        float r = R.part[0][j2] + R.part[1][j2] + R.part[2][j2] + R.part[3][j2];
        int pos = (T + j2 + shift) & NMASK;
        out[(size_t)b * NSAMP + pos] = r;
    }
}

extern "C" void kernel_launch(void* const* d_in, const int* in_sizes, int n_in,
                              void* d_out, int out_size, void* d_ws, size_t ws_size,
                              hipStream_t stream) {
    const float* x     = (const float*)d_in[0];
    const float* Wsw   = (const float*)d_in[1];
    const float* bsw   = (const float*)d_in[2];
    const float* Wf0   = (const float*)d_in[3];
    const float* bf0   = (const float*)d_in[4];
    const float* Wfv   = (const float*)d_in[5];
    const float* bfv   = (const float*)d_in[6];
    const float* Wamp  = (const float*)d_in[7];
    const float* bamp  = (const float*)d_in[8];
    const float* Wloc  = (const float*)d_in[9];
    const float* bloc  = (const float*)d_in[10];
    const float* usw   = (const float*)d_in[11];
    const float* uloc  = (const float*)d_in[12];
    const float* noise = (const float*)d_in[13];

    char* ws = (char*)d_ws;
    float*    PmodF  = (float*)(ws + OFF_PM);
    float*    vfreq  = (float*)(ws + OFF_V);
    unsigned short* tapsA = (unsigned short*)(ws + OFF_TA);
    float*    ampT   = (float*)(ws + OFF_A);
    unsigned* maxb   = (unsigned*)(ws + OFF_M);
    float*    swb    = (float*)(ws + OFF_SW);
    int*      shiftb = (int*)(ws + OFF_SH);
    float*    out    = (float*)d_out;

    amp_kernel<<<dim3(512), 128, 0, stream>>>(x, Wamp, bamp, ampT);
    prep_kernel<<<dim3(32), 128, 0, stream>>>(x, Wsw, bsw, Wf0, bf0, Wfv, bfv, Wloc, bloc,
                                              usw, uloc, PmodF, vfreq, tapsA, swb, shiftb, maxb);
    convmax_kernel<<<dim3(64, 32), 256, 0, stream>>>(noise, tapsA, swb, maxb);
    final_kernel<<<dim3(64, 32), 256, 0, stream>>>(noise, tapsA, PmodF, vfreq, ampT, maxb,
                                                   swb, shiftb, out);
}

// Round 5
// 87.724 us; speedup vs baseline: 4.3576x; 1.0549x over previous
//
#include <hip/hip_runtime.h>
#include <math.h>

typedef __attribute__((ext_vector_type(8))) short short8v;   // 8 bf16 (4 VGPRs)
typedef __attribute__((ext_vector_type(4))) float f32x4;

namespace {
constexpr int NSAMP = 32768;
constexpr int NMASK = NSAMP - 1;
constexpr float MIN_F_F = (float)(30.0 / 11025.0);
constexpr float SPAN_F  = (float)(3000.0 / 11025.0 - 30.0 / 11025.0);
constexpr float PI_F    = 3.14159265358979323846f;
constexpr double TWO_PI  = 6.283185307179586476925287;
constexpr double INV_2PI = 0.159154943091895335768884;
constexpr float INV_2PI_F = 0.15915494309189533577f;
constexpr float INV_SQRT_N = 0.00552427172801990295f; // 1/sqrt(32768)

// ws layout (bytes)
constexpr size_t OFF_PM = 0;                          // float PmodR [32][64][128]  1 MB (phase prefix, revolutions, fracted)
constexpr size_t OFF_V  = OFF_PM + 32*64*128*4;       // float vfreq [32][64][128]  1 MB (per-seg freq, revolutions)
constexpr size_t OFF_TA = OFF_V  + 32*64*128*4;       // u16   tapsA [32][64][128]  512 KB (bf16, reversed+swizzled)
constexpr size_t OFF_A  = OFF_TA + 32*64*128*2;       // float ampT  [32][128fr][128ch] 2 MB
constexpr size_t OFF_M  = OFF_A  + 32*128*128*4;      // uint  maxb  [2048]
constexpr size_t OFF_SW = OFF_M  + 2048*4;            // float swb   [32]
constexpr size_t OFF_SH = OFF_SW + 32*4;              // int   shiftb[32]
}

__device__ __forceinline__ float sigmoidf_(float z) { return 1.0f / (1.0f + expf(-z)); }
__device__ __forceinline__ float gumbelf_(float u) { return -logf(-logf(u + 1e-10f) + 1e-10f); }
__device__ __forceinline__ unsigned short f2bf(float f) {
    unsigned u = __float_as_uint(f);
    return (unsigned short)((u + 0x7FFFu + ((u >> 16) & 1u)) >> 16);
}
__device__ __forceinline__ float sinrev(float r) {   // r in [0,1): sin(2*pi*r)
#if __has_builtin(__builtin_amdgcn_sinf)
    return __builtin_amdgcn_sinf(r);
#else
    return __sinf(r * 6.2831853071795864769f);
#endif
}

// ---------------- setup: amp GEMV (blocks 0..255) || prep (blocks 256..287) ----------------
__launch_bounds__(256)
__global__ void setup_kernel(const float* __restrict__ x,
                             const float* __restrict__ Wsw, const float* __restrict__ bsw,
                             const float* __restrict__ Wf0, const float* __restrict__ bf0,
                             const float* __restrict__ Wfv, const float* __restrict__ bfv,
                             const float* __restrict__ Wamp, const float* __restrict__ bamp,
                             const float* __restrict__ Wloc, const float* __restrict__ bloc,
                             const float* __restrict__ usw, const float* __restrict__ uloc,
                             float* __restrict__ ampT,
                             float* __restrict__ PmodR, float* __restrict__ vfreq,
                             unsigned short* __restrict__ tapsA, float* __restrict__ swb,
                             int* __restrict__ shiftb, unsigned int* __restrict__ maxb) {
    int tid = threadIdx.x;
    __shared__ float xs[128], f0t[128];
    __shared__ float redA[128]; __shared__ int redI[128];
    __shared__ float red0[128], red1[128], red2[128];

    if (blockIdx.x < 256) {
        // ---- amp part: amp = (x@W_amp+b)^2 -> ampT[b][fr][ch] ----
        int bq = blockIdx.x >> 6;          // 0..3 (8 b's each)
        int jt = blockIdx.x & 63;          // 256-wide j tile
        int j = jt * 256 + tid;
        float acc[8];
        float bj = bamp[j];
#pragma unroll
        for (int b = 0; b < 8; ++b) acc[b] = bj;
        const float* xb = x + bq * 8 * 128;
#pragma unroll 8
        for (int d = 0; d < 128; ++d) {
            float wv = Wamp[(size_t)d * 16384 + j];
#pragma unroll
            for (int b = 0; b < 8; ++b) acc[b] = fmaf(xb[b * 128 + d], wv, acc[b]);
        }
        int ch = j >> 7, fr = j & 127;
#pragma unroll
        for (int b = 0; b < 8; ++b) {
            float a = acc[b];
            ampT[(size_t)(bq * 8 + b) * 16384 + fr * 128 + ch] = a * a;
        }
        return;
    }

    // ---- prep part: one block per b ----
    int b = blockIdx.x - 256;
    if (tid < 64) maxb[b * 64 + tid] = 0u;
    if (tid < 128) xs[tid] = x[b * 128 + tid];
    __syncthreads();

    // per-frame dots: threads 0..127 -> f0_var logits; 128..255 -> loc logits
    {
        int half = tid >> 7, fr = tid & 127;
        const float* W = half ? Wloc : Wfv;
        float a = (half ? bloc : bfv)[fr];
        for (int d = 0; d < 128; ++d) a = fmaf(xs[d], W[d * 128 + fr], a);
        if (half) { redA[fr] = sigmoidf_(a) + gumbelf_(uloc[b * 128 + fr]); redI[fr] = fr; }
        else      { f0t[fr] = sigmoidf_(a) * 2.0f - 1.0f; }   // f0var stash
    }
    if (tid < 128) {
        red0[tid] = xs[tid] * Wsw[tid * 2 + 0];
        red1[tid] = xs[tid] * Wsw[tid * 2 + 1];
        red2[tid] = xs[tid] * Wf0[tid];
    }
    __syncthreads();
    for (int off = 64; off > 0; off >>= 1) {
        if (tid < off) {
            red0[tid] += red0[tid + off];
            red1[tid] += red1[tid + off];
            red2[tid] += red2[tid + off];
            if (redA[tid + off] > redA[tid]) { redA[tid] = redA[tid + off]; redI[tid] = redI[tid + off]; }
        }
        __syncthreads();
    }
    float l0 = red0[0] + bsw[0], l1 = red1[0] + bsw[1];
    float g0 = gumbelf_(usw[b * 2 + 0]), g1 = gumbelf_(usw[b * 2 + 1]);
    float swv = (l0 + g0 >= l1 + g1) ? 1.0f : 0.0f;
    float sg = sigmoidf_(red2[0] + bf0[0]);
    float f0v = MIN_F_F + (sg * sg) * SPAN_F;
    if (tid == 0) { swb[b] = swv; shiftb[b] = redI[0] * 256; }
    if (tid < 128) {
        float f0var = f0t[tid];
        f0t[tid] = f0v + f0var * (f0v * 0.01f);
    }
    __syncthreads();

    // phase-prefix scan + taps, 4 waves x 16 h each; lane handles k=2l,2l+1
    int wave = tid >> 6, lane = tid & 63;
    int k0 = lane * 2, k1 = k0 + 1;
    for (int h = wave; h < 64; h += 4) {
        float hf = (float)(h + 1);
        size_t base = ((size_t)b * 64 + h) * 128;
        float vA = f0t[k0] * hf; vA = (vA > 1.0f) ? 0.0f : vA * PI_F;
        float vB = f0t[k1] * hf; vB = (vB > 1.0f) ? 0.0f : vB * PI_F;
        double v0d = (double)vA, v1d = (double)vB;
        double sc = v0d + v1d;
#pragma unroll
        for (int d = 1; d < 64; d <<= 1) {
            double o = __shfl_up(sc, d);
            if (lane >= d) sc += o;
        }
        // P(k) = 128*(2*S(k) - v[k]); S(2l+1)=sc, S(2l)=sc-v1
        double P0 = 128.0 * (2.0 * sc - 2.0 * v1d - v0d);
        double P1 = 128.0 * (2.0 * sc - v1d);
        double r0 = P0 * INV_2PI; r0 -= floor(r0);
        double r1 = P1 * INV_2PI; r1 -= floor(r1);
        PmodR[base + k0] = (float)r0;
        PmodR[base + k1] = (float)r1;
        vfreq[base + k0] = vA * INV_2PI_F;
        vfreq[base + k1] = vB * INV_2PI_F;
        // taps (depend only on v0 of this h)
        float v0_rad = __shfl(vA, 0);
        double v0rev = (double)v0_rad * INV_2PI;
#pragma unroll
        for (int kk = 0; kk < 2; ++kk) {
            int k = k0 + kk;
            float hwk = 0.54f - 0.46f * cosf(6.2831853071795864769f * (float)k / 128.0f);
            double rv = (double)(k + 1) * v0rev; rv -= floor(rv);
            float sv = __sinf((float)(rv * TWO_PI));
            float tv = sv * hwk * INV_SQRT_N;
            int c = k >> 3, e = 7 - (k & 7);
            tapsA[base + 8 * (c ^ (h & 7)) + e] = f2bf(tv);
        }
    }
}

// Conv core notes:
//   k-fill convention (same for A and B, so any HW k-permutation cancels):
//     frag[r] corresponds to logical k = 32*ks + 8*(lane>>4) + (7 - r)
//   A (taps) stored pre-reversed -> one aligned b128 per (mt,ks)
//   B: wsh[s][t] = w[t+s], chunk c stored at c^s -> one aligned, conflict-free b128

// ---------------- pass 1: MFMA circular FIR, 4 tiles/block, per-(b,h) row max ----------------
__launch_bounds__(256)
__global__ void convmax_kernel(const float* __restrict__ noise,
                               const unsigned short* __restrict__ tapsA,
                               const float* __restrict__ swb,
                               unsigned int* __restrict__ maxb) {
    int b = blockIdx.y;
    if (swb[b] == 0.0f) return;
    int tid = threadIdx.x;
    __shared__ short tapsL[64 * 128];
    __shared__ short wsh[8][640];
    __shared__ float wf[640];
    {
        const short8v* src = (const short8v*)(tapsA + ((size_t)b << 13));
        short8v* dst = (short8v*)tapsL;
        for (int i = tid; i < 1024; i += 256) dst[i] = src[i];
    }
    __syncthreads();
    int lane = tid & 63, w = tid >> 6;
    int g = lane >> 4, col = lane & 15, s_l = lane & 7, b3 = (lane >> 3) & 1;
    short8v fa[4][4];
#pragma unroll
    for (int mt = 0; mt < 4; ++mt)
#pragma unroll
        for (int ks = 0; ks < 4; ++ks) {
            int row = 16 * mt + col;
            int ch = (4 * ks + g) ^ (row & 7);
            fa[mt][ks] = *(const short8v*)&tapsL[row * 128 + 8 * ch];
        }
    float rm[16];
#pragma unroll
    for (int i = 0; i < 16; ++i) rm[i] = 0.0f;

    for (int tt = 0; tt < 4; ++tt) {
        int T = (blockIdx.x * 4 + tt) * 512;
        for (int i = tid; i < 640; i += 256)
            wf[i] = noise[(size_t)b * NSAMP + ((T - 127 + i) & NMASK)] * 2.0f - 1.0f;
        __syncthreads();   // wf ready; previous tile's wsh reads done
        for (int idx = tid; idx < 640; idx += 256) {
            int c = idx >> 3, s = idx & 7;
            short8v v;
#pragma unroll
            for (int e = 0; e < 8; ++e) {
                int t = 8 * c + e + s; t = t < 640 ? t : 639;
                v[e] = (short)f2bf(wf[t]);
            }
            *(short8v*)&wsh[s][8 * (c ^ s)] = v;
        }
        __syncthreads();
        for (int ntl = 0; ntl < 8; ++ntl) {
            int nt = w * 8 + ntl;
            short8v fb[4];
#pragma unroll
            for (int ks = 0; ks < 4; ++ks) {
                int t0 = 120 + 16 * nt - 32 * ks - 8 * g + 8 * b3;
                int ch = (t0 >> 3) ^ s_l;
                fb[ks] = *(const short8v*)&wsh[s_l][8 * ch];
            }
            f32x4 acc[4] = {{0,0,0,0},{0,0,0,0},{0,0,0,0},{0,0,0,0}};
#pragma unroll
            for (int ks = 0; ks < 4; ++ks)
#pragma unroll
                for (int mt = 0; mt < 4; ++mt)
                    acc[mt] = __builtin_amdgcn_mfma_f32_16x16x32_bf16(fa[mt][ks], fb[ks], acc[mt], 0, 0, 0);
#pragma unroll
            for (int mt = 0; mt < 4; ++mt)
#pragma unroll
                for (int q = 0; q < 4; ++q) rm[mt * 4 + q] = fmaxf(rm[mt * 4 + q], fabsf(acc[mt][q]));
        }
        __syncthreads();   // wsh reads done before next tile's wf overwrite? (wf only; wsh rebuilt after next sync)
    }
#pragma unroll
    for (int i = 0; i < 16; ++i) {
        float m = rm[i];
        m = fmaxf(m, __shfl_xor(m, 1));
        m = fmaxf(m, __shfl_xor(m, 2));
        m = fmaxf(m, __shfl_xor(m, 4));
        m = fmaxf(m, __shfl_xor(m, 8));
        if (col == 0) atomicMax(&maxb[b * 64 + 16 * (i >> 2) + 4 * g + (i & 3)], __float_as_uint(m));
    }
}

// ---------------- pass 2: fused MFMA conv + revolutions sine + amp lerp + reduce + shift ----
__launch_bounds__(256, 4)
__global__ void final_kernel(const float* __restrict__ noise,
                             const unsigned short* __restrict__ tapsA,
                             const float* __restrict__ PmodR, const float* __restrict__ vfreq,
                             const float* __restrict__ ampT,
                             const unsigned int* __restrict__ maxb,
                             const float* __restrict__ swb, const int* __restrict__ shiftb,
                             float* __restrict__ out) {
    int b = blockIdx.y;
    int T = blockIdx.x * 512, tid = threadIdx.x;
    if (swb[b] == 0.0f) {
        out[(size_t)b * NSAMP + T + tid] = 0.0f;
        out[(size_t)b * NSAMP + T + 256 + tid] = 0.0f;
        return;
    }
    __shared__ union { short tapsL[64 * 128]; float part[4][520]; } R;
    __shared__ short wsh[8][640];
    __shared__ float wf[640];
    __shared__ float4 seg[3][64];     // (vs_rev, dv_rev, Pb_rev, -) per (segment-slot, h)
    __shared__ float ampA[4][64], ampBn[4][64];  // SoA, invn folded into B

    int tile2 = blockIdx.x * 2, s0 = tile2 - 1;
    // ---- phase A: global loads ----
    for (int i = tid; i < 640; i += 256)
        wf[i] = noise[(size_t)b * NSAMP + ((T - 127 + i) & NMASK)] * 2.0f - 1.0f;
    {
        const short8v* src = (const short8v*)(tapsA + ((size_t)b << 13));
        short8v* dst = (short8v*)R.tapsL;
        for (int i = tid; i < 1024; i += 256) dst[i] = src[i];
    }
    {
        int ad = tid >> 6, ah = tid & 63;
        int afr = min(max(s0 + ad, 0), 127);
        float aAv = ampT[(size_t)b * 16384 + afr * 128 + ah];
        float aBv = ampT[(size_t)b * 16384 + afr * 128 + 64 + ah];
        float invn = 1.0f / (__uint_as_float(maxb[b * 64 + ah]) + 1e-8f);
        ampA[ad][ah] = aAv;
        ampBn[ad][ah] = aBv * invn;
    }
    if (tid < 192) {
        int dd = tid >> 6, h2 = tid & 63;
        size_t vb = ((size_t)(b * 64 + h2)) * 128;
        int s = min(max(s0 + dd, 0), 127), s1 = min(s + 1, 127);
        float vs = vfreq[vb + s], vs1 = vfreq[vb + s1];
        float4 sgv;
        sgv.x = vs;
        sgv.y = (vs1 - vs) * (1.0f / 512.0f);
        sgv.z = PmodR[vb + s];
        sgv.w = 0.0f;
        seg[dd][h2] = sgv;
    }
    __syncthreads();
    // ---- phase B: LDS->LDS builds + fragment/seg hoists ----
    for (int idx = tid; idx < 640; idx += 256) {
        int c = idx >> 3, s = idx & 7;
        short8v v;
#pragma unroll
        for (int e = 0; e < 8; ++e) {
            int t = 8 * c + e + s; t = t < 640 ? t : 639;
            v[e] = (short)f2bf(wf[t]);
        }
        *(short8v*)&wsh[s][8 * (c ^ s)] = v;
    }
    int lane = tid & 63, w = tid >> 6;
    int g = lane >> 4, col = lane & 15, s_l = lane & 7, b3 = (lane >> 3) & 1;
    short8v fa[4][4];
#pragma unroll
    for (int mt = 0; mt < 4; ++mt)
#pragma unroll
        for (int ks = 0; ks < 4; ++ks) {
            int row = 16 * mt + col;
            int ch = (4 * ks + g) ^ (row & 7);
            fa[mt][ks] = *(const short8v*)&R.tapsL[row * 128 + 8 * ch];
        }
    int dd = (w + 1) >> 1;                 // per-thread constant segment slot {0,1,1,2}
    bool head = (T + w * 128) < 128;       // only block 0, w==0
    float vsr[16], dvr[16], pbr[16];
#pragma unroll
    for (int mt = 0; mt < 4; ++mt)
#pragma unroll
        for (int q = 0; q < 4; ++q) {
            int i = mt * 4 + q, h = 16 * mt + 4 * g + q;
            float4 sgv = seg[dd][h];
            vsr[i] = sgv.x;
            dvr[i] = head ? 0.0f : sgv.y;
            pbr[i] = head ? (-128.0f * sgv.x) : sgv.z;   // head: p=(t+1)*v0 with m=t+129
        }
    __syncthreads();

    int shift = shiftb[b];
    for (int ntl = 0; ntl < 8; ++ntl) {
        int nt = w * 8 + ntl;
        short8v fb[4];
#pragma unroll
        for (int ks = 0; ks < 4; ++ks) {
            int t0 = 120 + 16 * nt - 32 * ks - 8 * g + 8 * b3;
            int ch = (t0 >> 3) ^ s_l;
            fb[ks] = *(const short8v*)&wsh[s_l][8 * ch];
        }
        f32x4 acc[4] = {{0,0,0,0},{0,0,0,0},{0,0,0,0},{0,0,0,0}};
#pragma unroll
        for (int ks = 0; ks < 4; ++ks)
#pragma unroll
            for (int mt = 0; mt < 4; ++mt)
                acc[mt] = __builtin_amdgcn_mfma_f32_16x16x32_bf16(fa[mt][ks], fb[ks], acc[mt], 0, 0, 0);

        int j = w * 128 + ntl * 16 + col;
        int t = T + j;
        float coords = ((float)t + 0.5f) * (1.0f / 256.0f) - 0.5f;
        coords = fminf(fmaxf(coords, 0.0f), 127.0f);
        float lof = floorf(coords);
        int lo = (int)lof; int hi = min(lo + 1, 127);
        float w1 = coords - lof;
        int dlo = lo - s0, dhi = hi - s0;
        float mp1 = (float)(((t - 128) & 255) + 1);
        float mp2 = mp1 * mp1;
        float psum = 0.0f;
#pragma unroll
        for (int mt = 0; mt < 4; ++mt) {
            int h4 = 16 * mt + 4 * g;
            f32x4 aloA = *(const f32x4*)&ampA[dlo][h4];
            f32x4 ahiA = *(const f32x4*)&ampA[dhi][h4];
            f32x4 aloB = *(const f32x4*)&ampBn[dlo][h4];
            f32x4 ahiB = *(const f32x4*)&ampBn[dhi][h4];
#pragma unroll
            for (int q = 0; q < 4; ++q) {
                int i = mt * 4 + q;
                float p = fmaf(mp2, dvr[i], fmaf(mp1, vsr[i], pbr[i]));
                p -= floorf(p);
                float sv = sinrev(p);
                float aA = fmaf(w1, ahiA[q] - aloA[q], aloA[q]);
                float aB = fmaf(w1, ahiB[q] - aloB[q], aloB[q]);
                psum = fmaf(sv, aA, psum);
                psum = fmaf(acc[mt][q], aB, psum);
            }
        }
        R.part[g][j] = psum;
    }
    __syncthreads();
#pragma unroll
    for (int rep = 0; rep < 2; ++rep) {
        int j2 = rep * 256 + tid;
        float r = R.part[0][j2] + R.part[1][j2] + R.part[2][j2] + R.part[3][j2];
        int pos = (T + j2 + shift) & NMASK;
        out[(size_t)b * NSAMP + pos] = r;
    }
}

extern "C" void kernel_launch(void* const* d_in, const int* in_sizes, int n_in,
                              void* d_out, int out_size, void* d_ws, size_t ws_size,
                              hipStream_t stream) {
    const float* x     = (const float*)d_in[0];
    const float* Wsw   = (const float*)d_in[1];
    const float* bsw   = (const float*)d_in[2];
    const float* Wf0   = (const float*)d_in[3];
    const float* bf0   = (const float*)d_in[4];
    const float* Wfv   = (const float*)d_in[5];
    const float* bfv   = (const float*)d_in[6];
    const float* Wamp  = (const float*)d_in[7];
    const float* bamp  = (const float*)d_in[8];
    const float* Wloc  = (const float*)d_in[9];
    const float* bloc  = (const float*)d_in[10];
    const float* usw   = (const float*)d_in[11];
    const float* uloc  = (const float*)d_in[12];
    const float* noise = (const float*)d_in[13];

    char* ws = (char*)d_ws;
    float*    PmodR  = (float*)(ws + OFF_PM);
    float*    vfreq  = (float*)(ws + OFF_V);
    unsigned short* tapsA = (unsigned short*)(ws + OFF_TA);
    float*    ampT   = (float*)(ws + OFF_A);
    unsigned* maxb   = (unsigned*)(ws + OFF_M);
    float*    swb    = (float*)(ws + OFF_SW);
    int*      shiftb = (int*)(ws + OFF_SH);
    float*    out    = (float*)d_out;

    setup_kernel<<<dim3(288), 256, 0, stream>>>(x, Wsw, bsw, Wf0, bf0, Wfv, bfv, Wamp, bamp,
                                                Wloc, bloc, usw, uloc, ampT,
                                                PmodR, vfreq, tapsA, swb, shiftb, maxb);
    convmax_kernel<<<dim3(16, 32), 256, 0, stream>>>(noise, tapsA, swb, maxb);
    final_kernel<<<dim3(64, 32), 256, 0, stream>>>(noise, tapsA, PmodR, vfreq, ampT, maxb,
                                                   swb, shiftb, out);
}

// Round 6
// 68.615 us; speedup vs baseline: 5.5711x; 1.2785x over previous
//
#include <hip/hip_runtime.h>
#include <math.h>

typedef __attribute__((ext_vector_type(8))) short short8v;   // 8 bf16 (4 VGPRs)
typedef __attribute__((ext_vector_type(4))) float f32x4;

namespace {
constexpr int NSAMP = 32768;
constexpr int NMASK = NSAMP - 1;
constexpr float MIN_F_F = (float)(30.0 / 11025.0);
constexpr float SPAN_F  = (float)(3000.0 / 11025.0 - 30.0 / 11025.0);
constexpr float PI_F    = 3.14159265358979323846f;
constexpr double TWO_PI  = 6.283185307179586476925287;
constexpr double INV_2PI = 0.159154943091895335768884;
constexpr float INV_2PI_F = 0.15915494309189533577f;
constexpr float INV_SQRT_N = 0.00552427172801990295f; // 1/sqrt(32768)

// ws layout (bytes)
constexpr size_t OFF_PM = 0;                          // float PmodR [32][64][128]  1 MB (phase prefix, revolutions, fracted)
constexpr size_t OFF_V  = OFF_PM + 32*64*128*4;       // float vfreq [32][64][128]  1 MB (per-seg freq, revolutions)
constexpr size_t OFF_TA = OFF_V  + 32*64*128*4;       // u16   tapsA [32][64][128]  512 KB (bf16, reversed+swizzled)
constexpr size_t OFF_A  = OFF_TA + 32*64*128*2;       // float ampT  [32][128fr][128ch] 2 MB
constexpr size_t OFF_M  = OFF_A  + 32*128*128*4;      // uint  maxb  [2048]
constexpr size_t OFF_SW = OFF_M  + 2048*4;            // float swb   [32]
constexpr size_t OFF_SH = OFF_SW + 32*4;              // int   shiftb[32]
}

__device__ __forceinline__ float sigmoidf_(float z) { return 1.0f / (1.0f + expf(-z)); }
__device__ __forceinline__ float gumbelf_(float u) { return -logf(-logf(u + 1e-10f) + 1e-10f); }
__device__ __forceinline__ unsigned short f2bf(float f) {
    unsigned u = __float_as_uint(f);
    return (unsigned short)((u + 0x7FFFu + ((u >> 16) & 1u)) >> 16);
}
__device__ __forceinline__ float sinrev(float r) {   // r in [0,1): sin(2*pi*r)
#if __has_builtin(__builtin_amdgcn_sinf)
    return __builtin_amdgcn_sinf(r);
#else
    return __sinf(r * 6.2831853071795864769f);
#endif
}

// ---------------- setup: amp GEMV (blocks 0..255) || prep (blocks 256..287) ----------------
__launch_bounds__(256)
__global__ void setup_kernel(const float* __restrict__ x,
                             const float* __restrict__ Wsw, const float* __restrict__ bsw,
                             const float* __restrict__ Wf0, const float* __restrict__ bf0,
                             const float* __restrict__ Wfv, const float* __restrict__ bfv,
                             const float* __restrict__ Wamp, const float* __restrict__ bamp,
                             const float* __restrict__ Wloc, const float* __restrict__ bloc,
                             const float* __restrict__ usw, const float* __restrict__ uloc,
                             float* __restrict__ ampT,
                             float* __restrict__ PmodR, float* __restrict__ vfreq,
                             unsigned short* __restrict__ tapsA, float* __restrict__ swb,
                             int* __restrict__ shiftb, unsigned int* __restrict__ maxb) {
    int tid = threadIdx.x;
    __shared__ float xs[128], f0t[128];
    __shared__ float redA[128]; __shared__ int redI[128];
    __shared__ float red0[128], red1[128], red2[128];

    if (blockIdx.x < 256) {
        // ---- amp part: amp = (x@W_amp+b)^2 -> ampT[b][fr][ch] ----
        int bq = blockIdx.x >> 6;          // 0..3 (8 b's each)
        int jt = blockIdx.x & 63;          // 256-wide j tile
        int j = jt * 256 + tid;
        float acc[8];
        float bj = bamp[j];
#pragma unroll
        for (int b = 0; b < 8; ++b) acc[b] = bj;
        const float* xb = x + bq * 8 * 128;
#pragma unroll 8
        for (int d = 0; d < 128; ++d) {
            float wv = Wamp[(size_t)d * 16384 + j];
#pragma unroll
            for (int b = 0; b < 8; ++b) acc[b] = fmaf(xb[b * 128 + d], wv, acc[b]);
        }
        int ch = j >> 7, fr = j & 127;
#pragma unroll
        for (int b = 0; b < 8; ++b) {
            float a = acc[b];
            ampT[(size_t)(bq * 8 + b) * 16384 + fr * 128 + ch] = a * a;
        }
        return;
    }

    // ---- prep part: one block per b ----
    int b = blockIdx.x - 256;
    if (tid < 64) maxb[b * 64 + tid] = 0u;
    if (tid < 128) xs[tid] = x[b * 128 + tid];
    __syncthreads();

    // per-frame dots: threads 0..127 -> f0_var logits; 128..255 -> loc logits
    {
        int half = tid >> 7, fr = tid & 127;
        const float* W = half ? Wloc : Wfv;
        float a = (half ? bloc : bfv)[fr];
        for (int d = 0; d < 128; ++d) a = fmaf(xs[d], W[d * 128 + fr], a);
        if (half) { redA[fr] = sigmoidf_(a) + gumbelf_(uloc[b * 128 + fr]); redI[fr] = fr; }
        else      { f0t[fr] = sigmoidf_(a) * 2.0f - 1.0f; }   // f0var stash
    }
    if (tid < 128) {
        red0[tid] = xs[tid] * Wsw[tid * 2 + 0];
        red1[tid] = xs[tid] * Wsw[tid * 2 + 1];
        red2[tid] = xs[tid] * Wf0[tid];
    }
    __syncthreads();
    for (int off = 64; off > 0; off >>= 1) {
        if (tid < off) {
            red0[tid] += red0[tid + off];
            red1[tid] += red1[tid + off];
            red2[tid] += red2[tid + off];
            if (redA[tid + off] > redA[tid]) { redA[tid] = redA[tid + off]; redI[tid] = redI[tid + off]; }
        }
        __syncthreads();
    }
    float l0 = red0[0] + bsw[0], l1 = red1[0] + bsw[1];
    float g0 = gumbelf_(usw[b * 2 + 0]), g1 = gumbelf_(usw[b * 2 + 1]);
    float swv = (l0 + g0 >= l1 + g1) ? 1.0f : 0.0f;
    float sg = sigmoidf_(red2[0] + bf0[0]);
    float f0v = MIN_F_F + (sg * sg) * SPAN_F;
    if (tid == 0) { swb[b] = swv; shiftb[b] = redI[0] * 256; }
    if (tid < 128) {
        float f0var = f0t[tid];
        f0t[tid] = f0v + f0var * (f0v * 0.01f);
    }
    __syncthreads();

    // phase-prefix scan + taps, 4 waves x 16 h each; lane handles k=2l,2l+1
    int wave = tid >> 6, lane = tid & 63;
    int k0 = lane * 2, k1 = k0 + 1;
    for (int h = wave; h < 64; h += 4) {
        float hf = (float)(h + 1);
        size_t base = ((size_t)b * 64 + h) * 128;
        float vA = f0t[k0] * hf; vA = (vA > 1.0f) ? 0.0f : vA * PI_F;
        float vB = f0t[k1] * hf; vB = (vB > 1.0f) ? 0.0f : vB * PI_F;
        double v0d = (double)vA, v1d = (double)vB;
        double sc = v0d + v1d;
#pragma unroll
        for (int d = 1; d < 64; d <<= 1) {
            double o = __shfl_up(sc, d);
            if (lane >= d) sc += o;
        }
        // P(k) = 128*(2*S(k) - v[k]); S(2l+1)=sc, S(2l)=sc-v1
        double P0 = 128.0 * (2.0 * sc - 2.0 * v1d - v0d);
        double P1 = 128.0 * (2.0 * sc - v1d);
        double r0 = P0 * INV_2PI; r0 -= floor(r0);
        double r1 = P1 * INV_2PI; r1 -= floor(r1);
        PmodR[base + k0] = (float)r0;
        PmodR[base + k1] = (float)r1;
        vfreq[base + k0] = vA * INV_2PI_F;
        vfreq[base + k1] = vB * INV_2PI_F;
        // taps (depend only on v0 of this h)
        float v0_rad = __shfl(vA, 0);
        double v0rev = (double)v0_rad * INV_2PI;
#pragma unroll
        for (int kk = 0; kk < 2; ++kk) {
            int k = k0 + kk;
            float hwk = 0.54f - 0.46f * cosf(6.2831853071795864769f * (float)k / 128.0f);
            double rv = (double)(k + 1) * v0rev; rv -= floor(rv);
            float sv = __sinf((float)(rv * TWO_PI));
            float tv = sv * hwk * INV_SQRT_N;
            int c = k >> 3, e = 7 - (k & 7);
            tapsA[base + 8 * (c ^ (h & 7)) + e] = f2bf(tv);
        }
    }
}

// Conv core notes:
//   k-fill convention (same for A and B, so any HW k-permutation cancels):
//     frag[r] corresponds to logical k = 32*ks + 8*(lane>>4) + (7 - r)
//   A (taps) stored pre-reversed -> one aligned b128 per (mt,ks)
//   B: wsh[s][t] = w[t+s], chunk c stored at c^s -> one aligned, conflict-free b128

// ---------------- pass 1: MFMA circular FIR, 4 tiles/block, per-(b,h) row max ----------------
__launch_bounds__(256)
__global__ void convmax_kernel(const float* __restrict__ noise,
                               const unsigned short* __restrict__ tapsA,
                               const float* __restrict__ swb,
                               unsigned int* __restrict__ maxb) {
    int b = blockIdx.y;
    if (swb[b] == 0.0f) return;
    int tid = threadIdx.x;
    __shared__ short tapsL[64 * 128];
    __shared__ short wsh[8][640];
    __shared__ float wf[640];
    {
        const short8v* src = (const short8v*)(tapsA + ((size_t)b << 13));
        short8v* dst = (short8v*)tapsL;
        for (int i = tid; i < 1024; i += 256) dst[i] = src[i];
    }
    __syncthreads();
    int lane = tid & 63, w = tid >> 6;
    int g = lane >> 4, col = lane & 15, s_l = lane & 7, b3 = (lane >> 3) & 1;
    short8v fa[4][4];
#pragma unroll
    for (int mt = 0; mt < 4; ++mt)
#pragma unroll
        for (int ks = 0; ks < 4; ++ks) {
            int row = 16 * mt + col;
            int ch = (4 * ks + g) ^ (row & 7);
            fa[mt][ks] = *(const short8v*)&tapsL[row * 128 + 8 * ch];
        }
    float rm[16];
#pragma unroll
    for (int i = 0; i < 16; ++i) rm[i] = 0.0f;

    for (int tt = 0; tt < 4; ++tt) {
        int T = (blockIdx.x * 4 + tt) * 512;
        for (int i = tid; i < 640; i += 256)
            wf[i] = noise[(size_t)b * NSAMP + ((T - 127 + i) & NMASK)] * 2.0f - 1.0f;
        __syncthreads();
        for (int idx = tid; idx < 640; idx += 256) {
            int c = idx >> 3, s = idx & 7;
            short8v v;
#pragma unroll
            for (int e = 0; e < 8; ++e) {
                int t = 8 * c + e + s; t = t < 640 ? t : 639;
                v[e] = (short)f2bf(wf[t]);
            }
            *(short8v*)&wsh[s][8 * (c ^ s)] = v;
        }
        __syncthreads();
        for (int ntl = 0; ntl < 8; ++ntl) {
            int nt = w * 8 + ntl;
            short8v fb[4];
#pragma unroll
            for (int ks = 0; ks < 4; ++ks) {
                int t0 = 120 + 16 * nt - 32 * ks - 8 * g + 8 * b3;
                int ch = (t0 >> 3) ^ s_l;
                fb[ks] = *(const short8v*)&wsh[s_l][8 * ch];
            }
            f32x4 acc[4] = {{0,0,0,0},{0,0,0,0},{0,0,0,0},{0,0,0,0}};
#pragma unroll
            for (int ks = 0; ks < 4; ++ks)
#pragma unroll
                for (int mt = 0; mt < 4; ++mt)
                    acc[mt] = __builtin_amdgcn_mfma_f32_16x16x32_bf16(fa[mt][ks], fb[ks], acc[mt], 0, 0, 0);
#pragma unroll
            for (int mt = 0; mt < 4; ++mt)
#pragma unroll
                for (int q = 0; q < 4; ++q) rm[mt * 4 + q] = fmaxf(rm[mt * 4 + q], fabsf(acc[mt][q]));
        }
        __syncthreads();
    }
#pragma unroll
    for (int i = 0; i < 16; ++i) {
        float m = rm[i];
        m = fmaxf(m, __shfl_xor(m, 1));
        m = fmaxf(m, __shfl_xor(m, 2));
        m = fmaxf(m, __shfl_xor(m, 4));
        m = fmaxf(m, __shfl_xor(m, 8));
        if (col == 0) atomicMax(&maxb[b * 64 + 16 * (i >> 2) + 4 * g + (i & 3)], __float_as_uint(m));
    }
}

// ---------------- pass 2: fused MFMA conv + revolutions sine + reg-hoisted amp lerp ----
__launch_bounds__(256)
__global__ void final_kernel(const float* __restrict__ noise,
                             const unsigned short* __restrict__ tapsA,
                             const float* __restrict__ PmodR, const float* __restrict__ vfreq,
                             const float* __restrict__ ampT,
                             const unsigned int* __restrict__ maxb,
                             const float* __restrict__ swb, const int* __restrict__ shiftb,
                             float* __restrict__ out) {
    int b = blockIdx.y;
    int T = blockIdx.x * 512, tid = threadIdx.x;
    if (swb[b] == 0.0f) {
        out[(size_t)b * NSAMP + T + tid] = 0.0f;
        out[(size_t)b * NSAMP + T + 256 + tid] = 0.0f;
        return;
    }
    __shared__ union { short tapsL[64 * 128]; float part[4][520]; } R;
    __shared__ short wsh[8][640];
    __shared__ float wf[640];
    __shared__ float4 seg[3][64];     // (vs_rev, dv_rev, Pb_rev, -) per (segment-slot, h)
    __shared__ float ampA[4][64], ampBn[4][64];  // SoA, invn folded into B

    int tile2 = blockIdx.x * 2, s0 = tile2 - 1;
    // ---- phase A: global loads ----
    for (int i = tid; i < 640; i += 256)
        wf[i] = noise[(size_t)b * NSAMP + ((T - 127 + i) & NMASK)] * 2.0f - 1.0f;
    {
        const short8v* src = (const short8v*)(tapsA + ((size_t)b << 13));
        short8v* dst = (short8v*)R.tapsL;
        for (int i = tid; i < 1024; i += 256) dst[i] = src[i];
    }
    {
        int ad = tid >> 6, ah = tid & 63;
        int afr = min(max(s0 + ad, 0), 127);
        float aAv = ampT[(size_t)b * 16384 + afr * 128 + ah];
        float aBv = ampT[(size_t)b * 16384 + afr * 128 + 64 + ah];
        float invn = 1.0f / (__uint_as_float(maxb[b * 64 + ah]) + 1e-8f);
        ampA[ad][ah] = aAv;
        ampBn[ad][ah] = aBv * invn;
    }
    if (tid < 192) {
        int dd = tid >> 6, h2 = tid & 63;
        size_t vb = ((size_t)(b * 64 + h2)) * 128;
        int s = min(max(s0 + dd, 0), 127), s1 = min(s + 1, 127);
        float vs = vfreq[vb + s], vs1 = vfreq[vb + s1];
        float4 sgv;
        sgv.x = vs;
        sgv.y = (vs1 - vs) * (1.0f / 512.0f);
        sgv.z = PmodR[vb + s];
        sgv.w = 0.0f;
        seg[dd][h2] = sgv;
    }
    __syncthreads();
    // ---- phase B: LDS->LDS builds + fragment/seg/amp hoists ----
    for (int idx = tid; idx < 640; idx += 256) {
        int c = idx >> 3, s = idx & 7;
        short8v v;
#pragma unroll
        for (int e = 0; e < 8; ++e) {
            int t = 8 * c + e + s; t = t < 640 ? t : 639;
            v[e] = (short)f2bf(wf[t]);
        }
        *(short8v*)&wsh[s][8 * (c ^ s)] = v;
    }
    int lane = tid & 63, w = tid >> 6;
    int g = lane >> 4, col = lane & 15, s_l = lane & 7, b3 = (lane >> 3) & 1;
    short8v fa[4][4];
#pragma unroll
    for (int mt = 0; mt < 4; ++mt)
#pragma unroll
        for (int ks = 0; ks < 4; ++ks) {
            int row = 16 * mt + col;
            int ch = (4 * ks + g) ^ (row & 7);
            fa[mt][ks] = *(const short8v*)&R.tapsL[row * 128 + 8 * ch];
        }
    int dd = (w + 1) >> 1;                 // per-thread constant segment slot {0,1,1,2}
    bool head = (T + w * 128) < 128;       // only block 0, w==0
    float vsr[16], dvr[16], pbr[16];
#pragma unroll
    for (int mt = 0; mt < 4; ++mt)
#pragma unroll
        for (int q = 0; q < 4; ++q) {
            int i = mt * 4 + q, h = 16 * mt + 4 * g + q;
            float4 sgv = seg[dd][h];
            vsr[i] = sgv.x;
            dvr[i] = head ? 0.0f : sgv.y;
            pbr[i] = head ? (-128.0f * sgv.x) : sgv.z;   // head: p=(t+1)*v0 with m=t+129
        }
    // per-thread frame slots are ntl-invariant: lo(t) = (t<128)?0:(t-128)>>8 is
    // constant over this thread's 8 ntl steps (128-sample span, T%512==0).
    int t_0 = T + w * 128 + col;
    int lo0 = (t_0 < 128) ? 0 : ((t_0 - 128) >> 8);
    int dlo = lo0 - s0;              // in {0,1,1,2} (+1 for head block); dhi=dlo+1 <= 3
    float loF = (float)lo0;
    f32x4 aloA[4], adA[4], aloB[4], adB[4];
#pragma unroll
    for (int mt = 0; mt < 4; ++mt) {
        int h4 = 16 * mt + 4 * g;
        aloA[mt] = *(const f32x4*)&ampA[dlo][h4];
        adA[mt]  = *(const f32x4*)&ampA[dlo + 1][h4] - aloA[mt];
        aloB[mt] = *(const f32x4*)&ampBn[dlo][h4];
        adB[mt]  = *(const f32x4*)&ampBn[dlo + 1][h4] - aloB[mt];
    }
    __syncthreads();

    int shift = shiftb[b];
    for (int ntl = 0; ntl < 8; ++ntl) {
        int nt = w * 8 + ntl;
        short8v fb[4];
#pragma unroll
        for (int ks = 0; ks < 4; ++ks) {
            int t0 = 120 + 16 * nt - 32 * ks - 8 * g + 8 * b3;
            int ch = (t0 >> 3) ^ s_l;
            fb[ks] = *(const short8v*)&wsh[s_l][8 * ch];
        }
        f32x4 acc[4] = {{0,0,0,0},{0,0,0,0},{0,0,0,0},{0,0,0,0}};
#pragma unroll
        for (int ks = 0; ks < 4; ++ks)
#pragma unroll
            for (int mt = 0; mt < 4; ++mt)
                acc[mt] = __builtin_amdgcn_mfma_f32_16x16x32_bf16(fa[mt][ks], fb[ks], acc[mt], 0, 0, 0);

        int j = w * 128 + ntl * 16 + col;
        int t = T + j;
        float coords = ((float)t + 0.5f) * (1.0f / 256.0f) - 0.5f;
        coords = fminf(fmaxf(coords, 0.0f), 127.0f);
        float w1 = coords - loF;
        float mp1 = (float)(((t - 128) & 255) + 1);
        float mp2 = mp1 * mp1;
        float psum = 0.0f;
#pragma unroll
        for (int mt = 0; mt < 4; ++mt) {
#pragma unroll
            for (int q = 0; q < 4; ++q) {
                int i = mt * 4 + q;
                float p = fmaf(mp2, dvr[i], fmaf(mp1, vsr[i], pbr[i]));
                p -= floorf(p);
                float sv = sinrev(p);
                float aA = fmaf(w1, adA[mt][q], aloA[mt][q]);
                float aB = fmaf(w1, adB[mt][q], aloB[mt][q]);
                psum = fmaf(sv, aA, psum);
                psum = fmaf(acc[mt][q], aB, psum);
            }
        }
        R.part[g][j] = psum;
    }
    __syncthreads();
#pragma unroll
    for (int rep = 0; rep < 2; ++rep) {
        int j2 = rep * 256 + tid;
        float r = R.part[0][j2] + R.part[1][j2] + R.part[2][j2] + R.part[3][j2];
        int pos = (T + j2 + shift) & NMASK;
        out[(size_t)b * NSAMP + pos] = r;
    }
}

extern "C" void kernel_launch(void* const* d_in, const int* in_sizes, int n_in,
                              void* d_out, int out_size, void* d_ws, size_t ws_size,
                              hipStream_t stream) {
    const float* x     = (const float*)d_in[0];
    const float* Wsw   = (const float*)d_in[1];
    const float* bsw   = (const float*)d_in[2];
    const float* Wf0   = (const float*)d_in[3];
    const float* bf0   = (const float*)d_in[4];
    const float* Wfv   = (const float*)d_in[5];
    const float* bfv   = (const float*)d_in[6];
    const float* Wamp  = (const float*)d_in[7];
    const float* bamp  = (const float*)d_in[8];
    const float* Wloc  = (const float*)d_in[9];
    const float* bloc  = (const float*)d_in[10];
    const float* usw   = (const float*)d_in[11];
    const float* uloc  = (const float*)d_in[12];
    const float* noise = (const float*)d_in[13];

    char* ws = (char*)d_ws;
    float*    PmodR  = (float*)(ws + OFF_PM);
    float*    vfreq  = (float*)(ws + OFF_V);
    unsigned short* tapsA = (unsigned short*)(ws + OFF_TA);
    float*    ampT   = (float*)(ws + OFF_A);
    unsigned* maxb   = (unsigned*)(ws + OFF_M);
    float*    swb    = (float*)(ws + OFF_SW);
    int*      shiftb = (int*)(ws + OFF_SH);
    float*    out    = (float*)d_out;

    setup_kernel<<<dim3(288), 256, 0, stream>>>(x, Wsw, bsw, Wf0, bf0, Wfv, bfv, Wamp, bamp,
                                                Wloc, bloc, usw, uloc, ampT,
                                                PmodR, vfreq, tapsA, swb, shiftb, maxb);
    convmax_kernel<<<dim3(16, 32), 256, 0, stream>>>(noise, tapsA, swb, maxb);
    final_kernel<<<dim3(64, 32), 256, 0, stream>>>(noise, tapsA, PmodR, vfreq, ampT, maxb,
                                                   swb, shiftb, out);
}